// Round 5
// baseline (309.519 us; speedup 1.0000x reference)
//
#include <hip/hip_runtime.h>
#include <hip/hip_fp16.h>

#define H 128
#define W 128
#define CIN 128
#define COUT 64
#define HW (H*W)
#define XW 130                    // padded spatial dim (y,x in [0,129])
#define FSL (XW*XW*64)            // feats2 elems per zb slice (NHWC f16)
#define XTD 144                   // xt padded dim

typedef __half f16;
typedef __attribute__((ext_vector_type(8)))  _Float16 h16x8;
typedef __attribute__((ext_vector_type(16))) float f32x16;

__device__ __forceinline__ float b2f(f16 v){ return __half2float(v); }
__device__ __forceinline__ f16  f2b(float v){ return __float2half_rn(v); }
__device__ __forceinline__ unsigned pack2(float a, float b){
    unsigned short ua = __builtin_bit_cast(unsigned short, f2b(a));
    unsigned short ub = __builtin_bit_cast(unsigned short, f2b(b));
    return (unsigned)ua | ((unsigned)ub << 16);
}
__device__ __forceinline__ unsigned short b16u(float v){
    return __builtin_bit_cast(unsigned short, f2b(v));
}
__device__ __forceinline__ __half2 uh2(unsigned u){
    return __builtin_bit_cast(__half2, u);
}
__device__ __forceinline__ unsigned h2u(__half2 v){
    return __builtin_bit_cast(unsigned, v);
}
__device__ __forceinline__ unsigned bcasth2(float v){
    __half h = __float2half_rn(v);
    return h2u(__halves2half2(h, h));
}
// async global->LDS, 16B per lane; lds dest must be linear in lane id
__device__ __forceinline__ void gld16(const void* g, void* l){
    __builtin_amdgcn_global_load_lds(
        (const __attribute__((address_space(1))) void*)g,
        (__attribute__((address_space(3))) void*)l, 16, 0, 0);
}

// ---------------------------------------------------------------------------
// k_prep: [0,1024) zero xt2; [1024,1600) wbt; [1600,1672) dwb2;
//         [1672,1704) cwb2; [1704,1740) pwb      (all tables packed f16 pairs)
// R5: dwb2 repacked [n][s][hf][oc][cl4]; cwb2 repacked [kc][hf][oc][cl4]
// so MFMA B-fragments read direct from global, lane-contiguous.
// ---------------------------------------------------------------------------
__global__ __launch_bounds__(256) void k_prep(
    const float* __restrict__ w1, const float* __restrict__ w2,
    const float* __restrict__ w3, const float* __restrict__ w4,
    const float* __restrict__ dw, const float* __restrict__ cw,
    const float* __restrict__ pw,
    uint4* __restrict__ xt4, unsigned* __restrict__ wbt,
    unsigned* __restrict__ dwb2, unsigned* __restrict__ cwb2,
    unsigned* __restrict__ pwb)
{
    int bid = blockIdx.x;
    int t = threadIdx.x;
    if (bid < 1024){
        const int n4 = (4*XTD*XTD*64)/4;        // 1327104
        for (int i = bid*256 + t; i < n4; i += 1024*256)
            xt4[i] = make_uint4(0,0,0,0);
    } else if (bid < 1600){
        int tid = (bid-1024)*256 + t;            // 147456 = 4*8*9*64*8
        int cpl = tid & 7;
        int oc  = (tid >> 3) & 63;
        int tap = (tid >> 9) % 9;
        int cg  = (tid / 4608) & 7;
        int d   = tid / 36864;
        const float* wt = (d==0)?w1:(d==1)?w2:(d==2)?w3:w4;
        int c = cg*8 + cpl;
        wbt[tid] = pack2(wt[((size_t)oc*CIN + 2*c  )*9 + tap],
                         wt[((size_t)oc*CIN + 2*c+1)*9 + tap]);
    } else if (bid < 1672){
        int i = (bid-1600)*256 + t;              // 18432: dwb2[n][s][hf][oc][cl4]
        int n = i>>11;
        int s = (i>>9)&3;
        int hf = (i>>8)&1;
        int oc = (i>>2)&63;
        int cl = i&3;
        int cp = s*8 + hf*4 + cl;                // channel-pair 0..31
        dwb2[i] = pack2(dw[((size_t)oc*64 + 2*cp  )*9 + n],
                        dw[((size_t)oc*64 + 2*cp+1)*9 + n]);
    } else if (bid < 1704){
        int i = (bid-1672)*256 + t;              // 8192: cwb2[kc][hf][oc][cl4]
        int kc = i>>9;
        int hf = (i>>8)&1;
        int oc = (i>>2)&63;
        int cl = i&3;
        int cp = kc*8 + hf*4 + cl;               // channel-pair 0..127
        cwb2[i] = pack2(cw[(size_t)oc*256 + 2*cp], cw[(size_t)oc*256 + 2*cp+1]);
    } else {
        int i = (bid-1704)*256 + t;              // 9216
        int cl = i & 3, oc = (i>>2)&31, hf = (i>>7)&1, cq = (i>>8)&3, tap = i>>10;
        int c = cq*16 + hf*8 + cl*2;
        unsigned v = 0u;
        if (oc < 18)
            v = pack2(pw[((size_t)oc*64 + c  )*9 + tap],
                      pw[((size_t)oc*64 + c+1)*9 + tap]);
        pwb[i] = v;
    }
}

// ---------------------------------------------------------------------------
// xprep: xt2[b][cg 8][y+8][col+8][cpl 8] u32 (interior). grid (128 y, 4 b).
// ---------------------------------------------------------------------------
__global__ __launch_bounds__(256) void k_xprep(
    const float* __restrict__ x, unsigned* __restrict__ xt)
{
    int y = blockIdx.x, b = blockIdx.y;
    int t = threadIdx.x;
    __shared__ float xsm[64*131];
    for (int ci0 = 0; ci0 < 128; ci0 += 64){
        for (int i=0;i<32;i++){
            int idx = t + 256*i;
            int col = idx & 127, ci = idx >> 7;
            xsm[ci*131 + col] = x[(((size_t)b*CIN + ci0+ci)*H + y)*W + col];
        }
        __syncthreads();
        for (int i=0;i<16;i++){
            int idx = t + 256*i;
            int cpg = idx & 31, col = idx >> 5;
            int cgg = (ci0 >> 4) + (cpg >> 3);
            int cpl = cpg & 7;
            unsigned u = pack2(xsm[(2*cpg)*131 + col], xsm[(2*cpg+1)*131 + col]);
            xt[((((size_t)b*8 + cgg)*XTD + y+8)*XTD + col+8)*8 + cpl] = u;
        }
        __syncthreads();
    }
}

// ---------------------------------------------------------------------------
// K1: dilated 3x3 conv via f16 MFMA implicit GEMM. grid 1024 1-D, XCD swizzle.
// (R4 structure: linear LDS + global_load_lds staging, conflict-free reads)
// ---------------------------------------------------------------------------
__global__ __launch_bounds__(256,3) void k_branch_mfma(
    const unsigned* __restrict__ xt, const unsigned* __restrict__ wbt,
    const float* __restrict__ b1, const float* __restrict__ b2,
    const float* __restrict__ b3, const float* __restrict__ b4,
    f16* __restrict__ feats2)
{
    int bid = blockIdx.x;
    int xcd = bid & 7;
    int j   = bid >> 3;
    int zb  = xcd + 8*(j & 1);
    int hp  = j >> 1;
    int d = zb >> 2, b = zb & 3;
    int dil = 2*d + 1;
    int h0 = hp*2;
    const float* bs = (d==0)?b1:(d==1)?b2:(d==2)?b3:b4;
    const float scale = (float)dil;

    __shared__ unsigned smem[6912 + 4608];     // As 27KB + Bs 18KB = 45KB
    unsigned* As = smem;
    unsigned* Bs = smem + 6912;
    const unsigned short* As16 = (const unsigned short*)As;
    const unsigned short* Bs16 = (const unsigned short*)Bs;

    int t = threadIdx.x;
    int lane = t & 63;
    int w = t >> 6;
    int l31 = lane & 31;
    int half = lane >> 5;

    f16* fb = feats2 + (size_t)zb*FSL;
    if (t < 32){
        int yy = h0 + 1 + (t>>4);
        int side = (t>>3)&1;
        int q = t & 7;
        uint4 z = make_uint4(0,0,0,0);
        *(uint4*)((unsigned short*)fb + ((size_t)yy*XW + side*129)*64 + q*8) = z;
    }
    if (hp == 0){
        uint4 z = make_uint4(0,0,0,0);
        for (int i=t; i<2080; i+=256){
            int row = i / 1040;
            int r = i % 1040;
            int xx = r >> 3, q = r & 7;
            *(uint4*)((unsigned short*)fb + ((size_t)(row*129)*XW + xx)*64 + q*8) = z;
        }
    }

    f32x16 acc[2][2];
    #pragma unroll
    for (int i=0;i<2;i++)
      #pragma unroll
      for (int jj=0;jj<2;jj++)
        #pragma unroll
        for (int e=0;e<16;e++) acc[i][jj][e] = 0.f;

    const unsigned* xtb_b = xt + (size_t)b*8*XTD*XTD*8;
    int r = w >> 1;
    int pxb = (w & 1) * 64;

    for (int cg=0; cg<8; cg++){
        const unsigned* xs_cg = xtb_b + (size_t)cg*XTD*XTD*8;
        #pragma unroll
        for (int i=0;i<7;i++){
            int idx4 = t + 256*i;
            if (idx4 < 1728){
                int row6 = idx4 / 288;
                int rem  = idx4 - row6*288;
                int hf   = rem / 144;
                int s    = rem - hf*144;
                int ky = row6 >> 1, rr = row6 & 1;
                int yy = h0 + rr + (ky-1)*dil + 8;
                gld16(xs_cg + ((size_t)yy*XTD + (s + 8 - dil))*8 + hf*4,
                      &As[idx4*4]);
            }
        }
        const unsigned* wb_cg = wbt + ((size_t)d*8 + cg)*4608;
        #pragma unroll
        for (int i=0;i<5;i++){
            int idx4 = t + 256*i;
            if (idx4 < 1152){
                int tap = idx4 >> 7;
                int hf  = (idx4 >> 6) & 1;
                int oc  = idx4 & 63;
                gld16(wb_cg + ((size_t)tap*64 + oc)*8 + hf*4,
                      &Bs[idx4*4]);
            }
        }
        __syncthreads();
        #pragma unroll
        for (int tap=0; tap<9; tap++){
            int ky = tap/3, kx = tap%3;
            int arow = ((ky*2 + r)*2 + half)*144;
            int brow = (tap*2 + half)*64;
            h16x8 a0  = *(const h16x8*)(As16 + (arow + pxb      + l31 + kx*dil)*8);
            h16x8 a1  = *(const h16x8*)(As16 + (arow + pxb + 32 + l31 + kx*dil)*8);
            h16x8 bb0 = *(const h16x8*)(Bs16 + (brow      + l31)*8);
            h16x8 bb1 = *(const h16x8*)(Bs16 + (brow + 32 + l31)*8);
            acc[0][0] = __builtin_amdgcn_mfma_f32_32x32x16_f16(a0, bb0, acc[0][0], 0,0,0);
            acc[0][1] = __builtin_amdgcn_mfma_f32_32x32x16_f16(a0, bb1, acc[0][1], 0,0,0);
            acc[1][0] = __builtin_amdgcn_mfma_f32_32x32x16_f16(a1, bb0, acc[1][0], 0,0,0);
            acc[1][1] = __builtin_amdgcn_mfma_f32_32x32x16_f16(a1, bb1, acc[1][1], 0,0,0);
        }
        __syncthreads();
    }

    unsigned short* ep = (unsigned short*)smem;   // 32KB overlay
    float bias0 = bs[l31], bias1 = bs[32 + l31];
    #pragma unroll
    for (int i=0;i<2;i++){
      #pragma unroll
      for (int jj=0;jj<2;jj++){
        int oc = jj*32 + l31;
        float bj = jj ? bias1 : bias0;
        #pragma unroll
        for (int rg=0; rg<4; rg++){
            int m0 = 64*w + 32*i + 8*rg + 4*half;
            #pragma unroll
            for (int e=0;e<4;e++)
                ep[(m0+e)*64 + oc] = b16u((acc[i][jj][4*rg+e] + bj)*scale);
        }
      }
    }
    __syncthreads();
    {
        int row = t >> 7, pxm = t & 127;
        unsigned short* drow = (unsigned short*)fb + ((size_t)(h0+1+row)*XW + pxm + 1)*64;
        const unsigned short* srow = ep + t*64;
        #pragma unroll
        for (int q=0;q<8;q++)
            *(uint4*)(drow + q*8) = *(const uint4*)(srow + q*8);
    }
}

// ---------------------------------------------------------------------------
// K2: 3x3 conv 64 -> 18 (offsets) via f16 MFMA, XCD swizzle.
// ---------------------------------------------------------------------------
__global__ __launch_bounds__(256,2) void k_offset_mfma(
    const f16* __restrict__ feats2,
    const unsigned* __restrict__ pwb,   // [tap][cq][hf][oc32][cl4] u32
    const float* __restrict__ pb,
    f16* __restrict__ offs)
{
    int bid = blockIdx.x;
    int xcd  = bid & 7;
    int h    = (bid >> 3) & 127;
    int pass = bid >> 10;
    int zb   = xcd + 8*pass;

    int t = threadIdx.x;
    int lane = t & 63, w = t >> 6;
    int l31 = lane & 31, half = lane >> 5;

    __shared__ unsigned short xs[3*132*68];   // 53.9 KB

    const unsigned short* fin = (const unsigned short*)(feats2 + (size_t)zb*FSL);
    for (int i=t; i<3120; i+=256){
        int row = i / 1040;
        int r   = i % 1040;
        int col = r >> 3, q = r & 7;
        uint4 v = *(const uint4*)(fin + ((size_t)(h+row)*XW + col)*64 + q*8);
        *(uint4*)&xs[(row*132 + col)*68 + q*8] = v;
    }
    __syncthreads();

    f32x16 acc;
    #pragma unroll
    for (int e=0;e<16;e++) acc[e] = 0.f;

    int pxw = 32*w + l31;
    #pragma unroll
    for (int tap=0; tap<9; tap++){
        int ky = tap/3, kx = tap%3;
        const unsigned short* arow = &xs[(ky*132 + pxw + kx)*68 + half*8];
        const unsigned* brow = pwb + (((size_t)tap*4)*2 + half)*128 + l31*4;
        #pragma unroll
        for (int cq=0; cq<4; cq++){
            h16x8 a  = *(const h16x8*)(arow + cq*16);
            h16x8 b0 = *(const h16x8*)(brow + cq*256);
            acc = __builtin_amdgcn_mfma_f32_32x32x16_f16(a, b0, acc, 0,0,0);
        }
    }
    __syncthreads();

    unsigned short* ep = (unsigned short*)xs;   // [oc 18][132 pad]
    if (l31 < 18){
        float bias = pb[l31];
        #pragma unroll
        for (int rg=0; rg<4; rg++){
            int m0 = 32*w + 4*half + 8*rg;
            #pragma unroll
            for (int e=0;e<4;e++)
                ep[l31*132 + m0+e] = b16u(acc[4*rg+e] + bias);
        }
    }
    __syncthreads();
    unsigned short* obase = (unsigned short*)(offs + (size_t)zb*18*HW) ;
    for (int i=t; i<288; i+=256){
        int oc = i >> 4, sg = i & 15;
        *(uint4*)(obase + (size_t)oc*HW + h*W + sg*8) = *(const uint4*)(ep + oc*132 + sg*8);
    }
}

// ---------------------------------------------------------------------------
// K3a: deform sampling + dw einsum via f16 MFMA.
// R5: 16-corner-load issue-all-first (one L2 latency per tap, not four);
// coords(n+1) computed during tap n's gather (Cd double-buffered);
// 2 barriers/tap (was 3); B read DIRECT from L1-hot dwb2 [n][s][hf][oc][4]
// (no B staging phase, no B LDS). grid 2048 1-D, XCD swizzle.
// ---------------------------------------------------------------------------
__device__ __forceinline__ void coords_px(
    const f16* __restrict__ obase, int h, int n, int px, unsigned* cp)
{
    float offy = b2f(obase[n*HW + px]);
    float offx = b2f(obase[(n+9)*HW + px]);
    float py  = (float)(h + n/3) + offy;
    float pxf = (float)(px + n%3) + offx;
    float fy = floorf(py), fx = floorf(pxf);
    float lty = fminf(fmaxf(fy,     0.f),129.f);
    float ltx = fminf(fmaxf(fx,     0.f),129.f);
    float rby = fminf(fmaxf(fy+1.f, 0.f),129.f);
    float rbx = fminf(fmaxf(fx+1.f, 0.f),129.f);
    float pyc = fminf(fmaxf(py,     0.f),129.f);
    float pxc = fminf(fmaxf(pxf,    0.f),129.f);
    float ay = 1.f + (lty-pyc), by = 1.f - (rby-pyc);
    float ax = 1.f + (ltx-pxc), bx = 1.f - (rbx-pxc);
    cp[0] = bcasth2(ay*ax);
    cp[1] = bcasth2(ay*bx);
    cp[2] = bcasth2(by*ax);
    cp[3] = bcasth2(by*bx);
    cp[4] = (unsigned)(((int)lty*XW + (int)ltx)*64);
    cp[5] = (unsigned)(((int)rbx - (int)ltx)*64);
    cp[6] = (unsigned)(((int)rby - (int)lty)*XW*64);
}

__global__ __launch_bounds__(256,4) void k_deform_mfma(
    const f16* __restrict__ feats2,
    const f16* __restrict__ offs,
    const unsigned* __restrict__ dwb2,  // [n][s][hf][oc][cl4] u32
    const float* __restrict__ db,
    f16* __restrict__ dout2)
{
    int bid = blockIdx.x;
    int xcd  = bid & 7;
    int h    = (bid >> 3) & 127;
    int pass = bid >> 10;
    int zb   = xcd + 8*pass;

    int t = threadIdx.x;
    int lane = t & 63, w = t >> 6;
    int l31 = lane & 31, half = lane >> 5;
    int pxg = t >> 3;                 // 0..31, pixel group (gather phase)
    int cq  = t & 7;                  // which 8-ch slice of the 64-ch line
    int sub_w = cq >> 1;              // A-frag sub (0..3)
    int hf8   = cq & 1;               // A-frag half (0..1)

    #define AROW 516                   // u32 row stride (8 rows)
    __shared__ unsigned smem_d[8*AROW + 2048];  // A 16.5KB + coords dbuf 8KB
    unsigned* Asu = smem_d;
    unsigned* Cd  = smem_d + 8*AROW;            // [2][px 128][8]

    const f16* obase = offs + (size_t)zb*18*HW + h*W;
    const unsigned short* fbase = (const unsigned short*)(feats2 + (size_t)zb*FSL);

    f32x16 acc0, acc1;
    #pragma unroll
    for (int e=0;e<16;e++){ acc0[e]=0.f; acc1[e]=0.f; }

    if (t < 128) coords_px(obase, h, 0, t, Cd + t*8);
    __syncthreads();

    for (int n=0; n<9; n++){
        unsigned* Cdc = Cd + (n&1)*1024;
        unsigned* Cdn = Cd + ((n+1)&1)*1024;

        // issue ALL 16 corner loads (4 slots x 4 corners) up-front
        unsigned LT[16], LB[16], RT[16], RB[16];
        #pragma unroll
        for (int s=0; s<4; s++){
            const unsigned* cp = Cdc + (s*32+pxg)*8;
            uint4 c1 = *(const uint4*)(cp + 4);
            int dxo = (int)c1.y, dyo = (int)c1.z;
            const unsigned short* fc = fbase + (int)c1.x + cq*8;
            *(uint4*)&LT[4*s] = *(const uint4*)(fc);
            *(uint4*)&LB[4*s] = *(const uint4*)(fc+dxo);
            *(uint4*)&RT[4*s] = *(const uint4*)(fc+dyo);
            *(uint4*)&RB[4*s] = *(const uint4*)(fc+dyo+dxo);
        }
        // coords for next tap overlap the in-flight gathers (other Cd buffer)
        if (n < 8 && t < 128) coords_px(obase, h, n+1, t, Cdn + t*8);

        // interp all 4 slots (weights re-read from LDS to save VGPRs)
        #pragma unroll
        for (int s=0; s<4; s++){
            int px = s*32 + pxg;
            uint4 c0 = *(const uint4*)(Cdc + px*8);
            __half2 wlt = uh2(c0.x);
            __half2 wlb = uh2(c0.y);
            __half2 wrt = uh2(c0.z);
            __half2 wrb = uh2(c0.w);
            unsigned pk[4];
            #pragma unroll
            for (int jq=0;jq<4;jq++){
                __half2 r = __hmul2(wlt, uh2(LT[4*s+jq]));
                r = __hfma2(wlb, uh2(LB[4*s+jq]), r);
                r = __hfma2(wrt, uh2(RT[4*s+jq]), r);
                r = __hfma2(wrb, uh2(RB[4*s+jq]), r);
                pk[jq] = h2u(r);
            }
            uint4 av; av.x=pk[0]; av.y=pk[1]; av.z=pk[2]; av.w=pk[3];
            *(uint4*)&Asu[(sub_w*2 + hf8)*AROW + px*4] = av;
        }
        __syncthreads();

        // MFMA phase: A from LDS, B direct from L1-hot dwb2
        const unsigned short* As16 = (const unsigned short*)Asu;
        const unsigned short* dnb16 = (const unsigned short*)(dwb2 + n*2048);
        #pragma unroll
        for (int s=0;s<4;s++){
            h16x8 a  = *(const h16x8*)(As16 + (s*2+half)*(AROW*2) + (32*w + l31)*8);
            h16x8 b0 = *(const h16x8*)(dnb16 + ((s*2+half)*64 + l31)*8);
            h16x8 b1 = *(const h16x8*)(dnb16 + ((s*2+half)*64 + 32+l31)*8);
            acc0 = __builtin_amdgcn_mfma_f32_32x32x16_f16(a, b0, acc0, 0,0,0);
            acc1 = __builtin_amdgcn_mfma_f32_32x32x16_f16(a, b1, acc1, 0,0,0);
        }
        __syncthreads();
    }

    // epilogue: +db, ep[px][oc] u16 == dout2 row layout, straight copy out
    unsigned short* ep = (unsigned short*)smem_d;   // overlay (safe: barrier above)
    #pragma unroll
    for (int nt=0; nt<2; nt++){
        int oc = nt*32 + l31;
        float bias = db[oc];
        const f32x16& A = nt ? acc1 : acc0;
        #pragma unroll
        for (int rg=0; rg<4; rg++){
            int m0 = 32*w + 4*half + 8*rg;
            #pragma unroll
            for (int e=0;e<4;e++)
                ep[(m0+e)*64 + oc] = b16u(A[4*rg+e] + bias);
        }
    }
    __syncthreads();
    uint4* dst = (uint4*)((unsigned short*)dout2 + ((size_t)zb*128 + h)*(128*64));
    #pragma unroll
    for (int i=0;i<4;i++)
        dst[t + 256*i] = ((const uint4*)ep)[t + 256*i];
    #undef AROW
}

// ---------------------------------------------------------------------------
// K3b: 1x1 conv 256 -> 64 + cb + ReLU via f16 MFMA. grid (128 h, 4 b).
// R5: A direct from dout2 (16-deep prefetch), B direct from L1-hot cwb2
// [kc][hf][oc][cl4]. Zero main-loop barriers (was 32), no LDS ping-pong.
// ---------------------------------------------------------------------------
__global__ __launch_bounds__(256,2) void k_combine_mfma(
    const f16* __restrict__ dout2,
    const unsigned* __restrict__ cwb2,  // [kc][hf][oc][cl4] u32
    const float* __restrict__ cb,
    float* __restrict__ out)
{
    int h = blockIdx.x, b = blockIdx.y;
    int t = threadIdx.x;
    int lane = t & 63, w = t >> 6, l31 = lane & 31, half = lane >> 5;

    __shared__ float ep2[64*132];   // 33.8 KB epilogue transpose

    f32x16 acc0, acc1;
    #pragma unroll
    for (int e=0;e<16;e++){ acc0[e]=0.f; acc1[e]=0.f; }

    const unsigned short* dbase0 = (const unsigned short*)dout2;
    const unsigned short* cb16 = (const unsigned short*)cwb2;
    size_t rowsel2 = ((size_t)b*128 + h)*128 + (32*w + l31);

    // issue all 16 A-fragment loads (16B each) up-front
    unsigned AV[64];
    #pragma unroll
    for (int kc=0; kc<16; kc++){
        *(uint4*)&AV[kc*4] = *(const uint4*)(
            dbase0 + (size_t)(kc>>2)*(4*HW*64) + rowsel2*64 + (kc&3)*16 + half*8);
    }
    #pragma unroll
    for (int kc=0; kc<16; kc++){
        h16x8 a  = __builtin_bit_cast(h16x8, *(uint4*)&AV[kc*4]);
        h16x8 b0 = *(const h16x8*)(cb16 + ((kc*2+half)*64 + l31)*8);
        h16x8 b1 = *(const h16x8*)(cb16 + ((kc*2+half)*64 + 32+l31)*8);
        acc0 = __builtin_amdgcn_mfma_f32_32x32x16_f16(a, b0, acc0, 0,0,0);
        acc1 = __builtin_amdgcn_mfma_f32_32x32x16_f16(a, b1, acc1, 0,0,0);
    }

    #pragma unroll
    for (int nt=0; nt<2; nt++){
        int oc = nt*32 + l31;
        float bias = cb[oc];
        const f32x16& A = nt ? acc1 : acc0;
        #pragma unroll
        for (int rg=0; rg<4; rg++){
            int m0 = 32*w + 4*half + 8*rg;
            #pragma unroll
            for (int e=0;e<4;e++)
                ep2[oc*132 + m0+e] = fmaxf(A[4*rg+e] + bias, 0.f);
        }
    }
    __syncthreads();
    for (int i=t; i<2048; i+=256){
        int oc = i>>5, sg = i&31;
        *(uint4*)&out[(((size_t)b*64+oc)*128 + h)*128 + sg*4] = *(const uint4*)&ep2[oc*132 + sg*4];
    }
}

extern "C" void kernel_launch(void* const* d_in, const int* in_sizes, int n_in,
                              void* d_out, int out_size, void* d_ws, size_t ws_size,
                              hipStream_t stream) {
    const float* x  = (const float*)d_in[0];
    const float* w1 = (const float*)d_in[1];
    const float* b1 = (const float*)d_in[2];
    const float* w2 = (const float*)d_in[3];
    const float* b2 = (const float*)d_in[4];
    const float* w3 = (const float*)d_in[5];
    const float* b3 = (const float*)d_in[6];
    const float* w4 = (const float*)d_in[7];
    const float* b4 = (const float*)d_in[8];
    const float* pw = (const float*)d_in[9];
    const float* pb = (const float*)d_in[10];
    const float* dw = (const float*)d_in[11];
    const float* db = (const float*)d_in[12];
    const float* cw = (const float*)d_in[13];
    const float* cb = (const float*)d_in[14];
    float* out = (float*)d_out;

    f16* feats2 = (f16*)d_ws;                               // 34.6 MB
    f16* offs   = feats2 + (size_t)16*FSL;                  // 9.4 MB
    f16* region2 = offs + (size_t)16*18*HW;
    f16* dout2  = region2;                                  // 33.55 MB
    unsigned* xt  = (unsigned*)region2;                     // 21.2 MB (dead before dout2)
    unsigned* wbt = xt + (size_t)4*8*XTD*XTD*8;             // 0.59 MB (dead before dout2)
    unsigned* dwb2 = (unsigned*)(dout2 + (size_t)16*128*128*64);  // 73.7 KB
    unsigned* cwb2 = dwb2 + 18432;                          // 32.8 KB
    unsigned* pwb  = cwb2 + 8192;                           // 36.9 KB

    k_prep        <<<dim3(1740),    256, 0, stream>>>(w1,w2,w3,w4, dw, cw, pw,
                                                      (uint4*)xt, wbt, dwb2, cwb2, pwb);
    k_xprep       <<<dim3(128,4),   256, 0, stream>>>(x, xt);
    k_branch_mfma <<<dim3(1024),    256, 0, stream>>>(xt, wbt, b1,b2,b3,b4, feats2);
    k_offset_mfma <<<dim3(2048),    256, 0, stream>>>(feats2, pwb, pb, offs);
    k_deform_mfma <<<dim3(2048),    256, 0, stream>>>(feats2, offs, dwb2, db, dout2);
    k_combine_mfma<<<dim3(128,4),   256, 0, stream>>>(dout2, cwb2, cb, out);
}

// Round 6
// 301.169 us; speedup vs baseline: 1.0277x; 1.0277x over previous
//
#include <hip/hip_runtime.h>
#include <hip/hip_fp16.h>

#define H 128
#define W 128
#define CIN 128
#define COUT 64
#define HW (H*W)
#define XW 130                    // padded spatial dim (y,x in [0,129])
#define FSL (XW*XW*64)            // feats2 elems per zb slice (NHWC f16)
#define XTD 144                   // xt padded dim

typedef __half f16;
typedef __attribute__((ext_vector_type(8)))  _Float16 h16x8;
typedef __attribute__((ext_vector_type(16))) float f32x16;

__device__ __forceinline__ float b2f(f16 v){ return __half2float(v); }
__device__ __forceinline__ f16  f2b(float v){ return __float2half_rn(v); }
__device__ __forceinline__ unsigned pack2(float a, float b){
    unsigned short ua = __builtin_bit_cast(unsigned short, f2b(a));
    unsigned short ub = __builtin_bit_cast(unsigned short, f2b(b));
    return (unsigned)ua | ((unsigned)ub << 16);
}
__device__ __forceinline__ unsigned short b16u(float v){
    return __builtin_bit_cast(unsigned short, f2b(v));
}
__device__ __forceinline__ __half2 uh2(unsigned u){
    return __builtin_bit_cast(__half2, u);
}
__device__ __forceinline__ unsigned h2u(__half2 v){
    return __builtin_bit_cast(unsigned, v);
}
__device__ __forceinline__ unsigned bcasth2(float v){
    __half h = __float2half_rn(v);
    return h2u(__halves2half2(h, h));
}
// async global->LDS, 16B per lane; lds dest must be linear in lane id
__device__ __forceinline__ void gld16(const void* g, void* l){
    __builtin_amdgcn_global_load_lds(
        (const __attribute__((address_space(1))) void*)g,
        (__attribute__((address_space(3))) void*)l, 16, 0, 0);
}

// ---------------------------------------------------------------------------
// k_prep: [0,1024) zero xt2; [1024,1600) wbt; [1600,1672) dwb2;
//         [1672,1704) cwb2; [1704,1740) pwb      (all tables packed f16 pairs)
// dwb2 [n][s][hf][oc][cl4]; cwb2 [kc][hf][oc][cl4]: B-frags direct-from-global.
// ---------------------------------------------------------------------------
__global__ __launch_bounds__(256) void k_prep(
    const float* __restrict__ w1, const float* __restrict__ w2,
    const float* __restrict__ w3, const float* __restrict__ w4,
    const float* __restrict__ dw, const float* __restrict__ cw,
    const float* __restrict__ pw,
    uint4* __restrict__ xt4, unsigned* __restrict__ wbt,
    unsigned* __restrict__ dwb2, unsigned* __restrict__ cwb2,
    unsigned* __restrict__ pwb)
{
    int bid = blockIdx.x;
    int t = threadIdx.x;
    if (bid < 1024){
        const int n4 = (4*XTD*XTD*64)/4;        // 1327104
        for (int i = bid*256 + t; i < n4; i += 1024*256)
            xt4[i] = make_uint4(0,0,0,0);
    } else if (bid < 1600){
        int tid = (bid-1024)*256 + t;            // 147456 = 4*8*9*64*8
        int cpl = tid & 7;
        int oc  = (tid >> 3) & 63;
        int tap = (tid >> 9) % 9;
        int cg  = (tid / 4608) & 7;
        int d   = tid / 36864;
        const float* wt = (d==0)?w1:(d==1)?w2:(d==2)?w3:w4;
        int c = cg*8 + cpl;
        wbt[tid] = pack2(wt[((size_t)oc*CIN + 2*c  )*9 + tap],
                         wt[((size_t)oc*CIN + 2*c+1)*9 + tap]);
    } else if (bid < 1672){
        int i = (bid-1600)*256 + t;              // 18432: dwb2[n][s][hf][oc][cl4]
        int n = i>>11;
        int s = (i>>9)&3;
        int hf = (i>>8)&1;
        int oc = (i>>2)&63;
        int cl = i&3;
        int cp = s*8 + hf*4 + cl;                // channel-pair 0..31
        dwb2[i] = pack2(dw[((size_t)oc*64 + 2*cp  )*9 + n],
                        dw[((size_t)oc*64 + 2*cp+1)*9 + n]);
    } else if (bid < 1704){
        int i = (bid-1672)*256 + t;              // 8192: cwb2[kc][hf][oc][cl4]
        int kc = i>>9;
        int hf = (i>>8)&1;
        int oc = (i>>2)&63;
        int cl = i&3;
        int cp = kc*8 + hf*4 + cl;               // channel-pair 0..127
        cwb2[i] = pack2(cw[(size_t)oc*256 + 2*cp], cw[(size_t)oc*256 + 2*cp+1]);
    } else {
        int i = (bid-1704)*256 + t;              // 9216
        int cl = i & 3, oc = (i>>2)&31, hf = (i>>7)&1, cq = (i>>8)&3, tap = i>>10;
        int c = cq*16 + hf*8 + cl*2;
        unsigned v = 0u;
        if (oc < 18)
            v = pack2(pw[((size_t)oc*64 + c  )*9 + tap],
                      pw[((size_t)oc*64 + c+1)*9 + tap]);
        pwb[i] = v;
    }
}

// ---------------------------------------------------------------------------
// xprep: xt2[b][cg 8][y+8][col+8][cpl 8] u32 (interior). grid (128 y, 4 b).
// ---------------------------------------------------------------------------
__global__ __launch_bounds__(256) void k_xprep(
    const float* __restrict__ x, unsigned* __restrict__ xt)
{
    int y = blockIdx.x, b = blockIdx.y;
    int t = threadIdx.x;
    __shared__ float xsm[64*131];
    for (int ci0 = 0; ci0 < 128; ci0 += 64){
        for (int i=0;i<32;i++){
            int idx = t + 256*i;
            int col = idx & 127, ci = idx >> 7;
            xsm[ci*131 + col] = x[(((size_t)b*CIN + ci0+ci)*H + y)*W + col];
        }
        __syncthreads();
        for (int i=0;i<16;i++){
            int idx = t + 256*i;
            int cpg = idx & 31, col = idx >> 5;
            int cgg = (ci0 >> 4) + (cpg >> 3);
            int cpl = cpg & 7;
            unsigned u = pack2(xsm[(2*cpg)*131 + col], xsm[(2*cpg+1)*131 + col]);
            xt[((((size_t)b*8 + cgg)*XTD + y+8)*XTD + col+8)*8 + cpl] = u;
        }
        __syncthreads();
    }
}

// ---------------------------------------------------------------------------
// K1: dilated 3x3 conv via f16 MFMA implicit GEMM. grid 1024 1-D, XCD swizzle.
// (R4 structure: linear LDS + global_load_lds staging, conflict-free reads)
// ---------------------------------------------------------------------------
__global__ __launch_bounds__(256,3) void k_branch_mfma(
    const unsigned* __restrict__ xt, const unsigned* __restrict__ wbt,
    const float* __restrict__ b1, const float* __restrict__ b2,
    const float* __restrict__ b3, const float* __restrict__ b4,
    f16* __restrict__ feats2)
{
    int bid = blockIdx.x;
    int xcd = bid & 7;
    int j   = bid >> 3;
    int zb  = xcd + 8*(j & 1);
    int hp  = j >> 1;
    int d = zb >> 2, b = zb & 3;
    int dil = 2*d + 1;
    int h0 = hp*2;
    const float* bs = (d==0)?b1:(d==1)?b2:(d==2)?b3:b4;
    const float scale = (float)dil;

    __shared__ unsigned smem[6912 + 4608];     // As 27KB + Bs 18KB = 45KB
    unsigned* As = smem;
    unsigned* Bs = smem + 6912;
    const unsigned short* As16 = (const unsigned short*)As;
    const unsigned short* Bs16 = (const unsigned short*)Bs;

    int t = threadIdx.x;
    int lane = t & 63;
    int w = t >> 6;
    int l31 = lane & 31;
    int half = lane >> 5;

    f16* fb = feats2 + (size_t)zb*FSL;
    if (t < 32){
        int yy = h0 + 1 + (t>>4);
        int side = (t>>3)&1;
        int q = t & 7;
        uint4 z = make_uint4(0,0,0,0);
        *(uint4*)((unsigned short*)fb + ((size_t)yy*XW + side*129)*64 + q*8) = z;
    }
    if (hp == 0){
        uint4 z = make_uint4(0,0,0,0);
        for (int i=t; i<2080; i+=256){
            int row = i / 1040;
            int r = i % 1040;
            int xx = r >> 3, q = r & 7;
            *(uint4*)((unsigned short*)fb + ((size_t)(row*129)*XW + xx)*64 + q*8) = z;
        }
    }

    f32x16 acc[2][2];
    #pragma unroll
    for (int i=0;i<2;i++)
      #pragma unroll
      for (int jj=0;jj<2;jj++)
        #pragma unroll
        for (int e=0;e<16;e++) acc[i][jj][e] = 0.f;

    const unsigned* xtb_b = xt + (size_t)b*8*XTD*XTD*8;
    int r = w >> 1;
    int pxb = (w & 1) * 64;

    for (int cg=0; cg<8; cg++){
        const unsigned* xs_cg = xtb_b + (size_t)cg*XTD*XTD*8;
        #pragma unroll
        for (int i=0;i<7;i++){
            int idx4 = t + 256*i;
            if (idx4 < 1728){
                int row6 = idx4 / 288;
                int rem  = idx4 - row6*288;
                int hf   = rem / 144;
                int s    = rem - hf*144;
                int ky = row6 >> 1, rr = row6 & 1;
                int yy = h0 + rr + (ky-1)*dil + 8;
                gld16(xs_cg + ((size_t)yy*XTD + (s + 8 - dil))*8 + hf*4,
                      &As[idx4*4]);
            }
        }
        const unsigned* wb_cg = wbt + ((size_t)d*8 + cg)*4608;
        #pragma unroll
        for (int i=0;i<5;i++){
            int idx4 = t + 256*i;
            if (idx4 < 1152){
                int tap = idx4 >> 7;
                int hf  = (idx4 >> 6) & 1;
                int oc  = idx4 & 63;
                gld16(wb_cg + ((size_t)tap*64 + oc)*8 + hf*4,
                      &Bs[idx4*4]);
            }
        }
        __syncthreads();
        #pragma unroll
        for (int tap=0; tap<9; tap++){
            int ky = tap/3, kx = tap%3;
            int arow = ((ky*2 + r)*2 + half)*144;
            int brow = (tap*2 + half)*64;
            h16x8 a0  = *(const h16x8*)(As16 + (arow + pxb      + l31 + kx*dil)*8);
            h16x8 a1  = *(const h16x8*)(As16 + (arow + pxb + 32 + l31 + kx*dil)*8);
            h16x8 bb0 = *(const h16x8*)(Bs16 + (brow      + l31)*8);
            h16x8 bb1 = *(const h16x8*)(Bs16 + (brow + 32 + l31)*8);
            acc[0][0] = __builtin_amdgcn_mfma_f32_32x32x16_f16(a0, bb0, acc[0][0], 0,0,0);
            acc[0][1] = __builtin_amdgcn_mfma_f32_32x32x16_f16(a0, bb1, acc[0][1], 0,0,0);
            acc[1][0] = __builtin_amdgcn_mfma_f32_32x32x16_f16(a1, bb0, acc[1][0], 0,0,0);
            acc[1][1] = __builtin_amdgcn_mfma_f32_32x32x16_f16(a1, bb1, acc[1][1], 0,0,0);
        }
        __syncthreads();
    }

    unsigned short* ep = (unsigned short*)smem;   // 32KB overlay
    float bias0 = bs[l31], bias1 = bs[32 + l31];
    #pragma unroll
    for (int i=0;i<2;i++){
      #pragma unroll
      for (int jj=0;jj<2;jj++){
        int oc = jj*32 + l31;
        float bj = jj ? bias1 : bias0;
        #pragma unroll
        for (int rg=0; rg<4; rg++){
            int m0 = 64*w + 32*i + 8*rg + 4*half;
            #pragma unroll
            for (int e=0;e<4;e++)
                ep[(m0+e)*64 + oc] = b16u((acc[i][jj][4*rg+e] + bj)*scale);
        }
      }
    }
    __syncthreads();
    {
        int row = t >> 7, pxm = t & 127;
        unsigned short* drow = (unsigned short*)fb + ((size_t)(h0+1+row)*XW + pxm + 1)*64;
        const unsigned short* srow = ep + t*64;
        #pragma unroll
        for (int q=0;q<8;q++)
            *(uint4*)(drow + q*8) = *(const uint4*)(srow + q*8);
    }
}

// ---------------------------------------------------------------------------
// K2: 3x3 conv 64 -> 18 (offsets) via f16 MFMA, XCD swizzle.
// ---------------------------------------------------------------------------
__global__ __launch_bounds__(256,2) void k_offset_mfma(
    const f16* __restrict__ feats2,
    const unsigned* __restrict__ pwb,   // [tap][cq][hf][oc32][cl4] u32
    const float* __restrict__ pb,
    f16* __restrict__ offs)
{
    int bid = blockIdx.x;
    int xcd  = bid & 7;
    int h    = (bid >> 3) & 127;
    int pass = bid >> 10;
    int zb   = xcd + 8*pass;

    int t = threadIdx.x;
    int lane = t & 63, w = t >> 6;
    int l31 = lane & 31, half = lane >> 5;

    __shared__ unsigned short xs[3*132*68];   // 53.9 KB

    const unsigned short* fin = (const unsigned short*)(feats2 + (size_t)zb*FSL);
    for (int i=t; i<3120; i+=256){
        int row = i / 1040;
        int r   = i % 1040;
        int col = r >> 3, q = r & 7;
        uint4 v = *(const uint4*)(fin + ((size_t)(h+row)*XW + col)*64 + q*8);
        *(uint4*)&xs[(row*132 + col)*68 + q*8] = v;
    }
    __syncthreads();

    f32x16 acc;
    #pragma unroll
    for (int e=0;e<16;e++) acc[e] = 0.f;

    int pxw = 32*w + l31;
    #pragma unroll
    for (int tap=0; tap<9; tap++){
        int ky = tap/3, kx = tap%3;
        const unsigned short* arow = &xs[(ky*132 + pxw + kx)*68 + half*8];
        const unsigned* brow = pwb + (((size_t)tap*4)*2 + half)*128 + l31*4;
        #pragma unroll
        for (int cq=0; cq<4; cq++){
            h16x8 a  = *(const h16x8*)(arow + cq*16);
            h16x8 b0 = *(const h16x8*)(brow + cq*256);
            acc = __builtin_amdgcn_mfma_f32_32x32x16_f16(a, b0, acc, 0,0,0);
        }
    }
    __syncthreads();

    unsigned short* ep = (unsigned short*)xs;   // [oc 18][132 pad]
    if (l31 < 18){
        float bias = pb[l31];
        #pragma unroll
        for (int rg=0; rg<4; rg++){
            int m0 = 32*w + 4*half + 8*rg;
            #pragma unroll
            for (int e=0;e<4;e++)
                ep[l31*132 + m0+e] = b16u(acc[4*rg+e] + bias);
        }
    }
    __syncthreads();
    unsigned short* obase = (unsigned short*)(offs + (size_t)zb*18*HW) ;
    for (int i=t; i<288; i+=256){
        int oc = i >> 4, sg = i & 15;
        *(uint4*)(obase + (size_t)oc*HW + h*W + sg*8) = *(const uint4*)(ep + oc*132 + sg*8);
    }
}

// ---------------------------------------------------------------------------
// K3a: deform sampling + dw einsum via f16 MFMA.
// R6: per-slot gather (4 corners live -> no spill) + B direct from L1-hot
// dwb2 [n][s][hf][oc][4] + coords(n+1) double-buffered (2 barriers/tap).
// LDS 24.7KB -> 6 blocks/CU, __launch_bounds__(256,6).
// grid 2048 1-D, XCD swizzle.
// ---------------------------------------------------------------------------
__device__ __forceinline__ void coords_px(
    const f16* __restrict__ obase, int h, int n, int px, unsigned* cp)
{
    float offy = b2f(obase[n*HW + px]);
    float offx = b2f(obase[(n+9)*HW + px]);
    float py  = (float)(h + n/3) + offy;
    float pxf = (float)(px + n%3) + offx;
    float fy = floorf(py), fx = floorf(pxf);
    float lty = fminf(fmaxf(fy,     0.f),129.f);
    float ltx = fminf(fmaxf(fx,     0.f),129.f);
    float rby = fminf(fmaxf(fy+1.f, 0.f),129.f);
    float rbx = fminf(fmaxf(fx+1.f, 0.f),129.f);
    float pyc = fminf(fmaxf(py,     0.f),129.f);
    float pxc = fminf(fmaxf(pxf,    0.f),129.f);
    float ay = 1.f + (lty-pyc), by = 1.f - (rby-pyc);
    float ax = 1.f + (ltx-pxc), bx = 1.f - (rbx-pxc);
    cp[0] = bcasth2(ay*ax);
    cp[1] = bcasth2(ay*bx);
    cp[2] = bcasth2(by*ax);
    cp[3] = bcasth2(by*bx);
    cp[4] = (unsigned)(((int)lty*XW + (int)ltx)*64);
    cp[5] = (unsigned)(((int)rbx - (int)ltx)*64);
    cp[6] = (unsigned)(((int)rby - (int)lty)*XW*64);
}

__global__ __launch_bounds__(256,6) void k_deform_mfma(
    const f16* __restrict__ feats2,
    const f16* __restrict__ offs,
    const unsigned* __restrict__ dwb2,  // [n][s][hf][oc][cl4] u32
    const float* __restrict__ db,
    f16* __restrict__ dout2)
{
    int bid = blockIdx.x;
    int xcd  = bid & 7;
    int h    = (bid >> 3) & 127;
    int pass = bid >> 10;
    int zb   = xcd + 8*pass;

    int t = threadIdx.x;
    int lane = t & 63, w = t >> 6;
    int l31 = lane & 31, half = lane >> 5;
    int pxg = t >> 3;                 // 0..31, pixel group (gather phase)
    int cq  = t & 7;                  // which 8-ch slice of the 64-ch line
    int sub_w = cq >> 1;              // A-frag sub (0..3)
    int hf8   = cq & 1;               // A-frag half (0..1)

    #define AROW 516                   // u32 row stride (8 rows)
    __shared__ unsigned smem_d[8*AROW + 2048];  // A 16.5KB + coords dbuf 8KB
    unsigned* Asu = smem_d;
    unsigned* Cd  = smem_d + 8*AROW;            // [2][px 128][8]

    const f16* obase = offs + (size_t)zb*18*HW + h*W;
    const unsigned short* fbase = (const unsigned short*)(feats2 + (size_t)zb*FSL);

    f32x16 acc0, acc1;
    #pragma unroll
    for (int e=0;e<16;e++){ acc0[e]=0.f; acc1[e]=0.f; }

    if (t < 128) coords_px(obase, h, 0, t, Cd + t*8);
    __syncthreads();

    for (int n=0; n<9; n++){
        unsigned* Cdc = Cd + (n&1)*1024;
        unsigned* Cdn = Cd + ((n+1)&1)*1024;

        // gather: per-slot 4-corner load + packed-f16 interp (<=16 corner regs)
        #pragma unroll
        for (int s=0; s<4; s++){
            int px = s*32 + pxg;
            const unsigned* cp = Cdc + px*8;
            uint4 c0 = *(const uint4*)cp;
            uint4 c1 = *(const uint4*)(cp + 4);
            __half2 wlt = uh2(c0.x);
            __half2 wlb = uh2(c0.y);
            __half2 wrt = uh2(c0.z);
            __half2 wrb = uh2(c0.w);
            int dxo = (int)c1.y, dyo = (int)c1.z;
            const unsigned short* fc = fbase + (int)c1.x + cq*8;
            unsigned LT[4], LB[4], RT[4], RB[4];
            *(uint4*)LT = *(const uint4*)(fc);
            *(uint4*)LB = *(const uint4*)(fc+dxo);
            *(uint4*)RT = *(const uint4*)(fc+dyo);
            *(uint4*)RB = *(const uint4*)(fc+dyo+dxo);
            unsigned pk[4];
            #pragma unroll
            for (int jq=0;jq<4;jq++){
                __half2 r = __hmul2(wlt, uh2(LT[jq]));
                r = __hfma2(wlb, uh2(LB[jq]), r);
                r = __hfma2(wrt, uh2(RT[jq]), r);
                r = __hfma2(wrb, uh2(RB[jq]), r);
                pk[jq] = h2u(r);
            }
            uint4 av; av.x=pk[0]; av.y=pk[1]; av.z=pk[2]; av.w=pk[3];
            *(uint4*)&Asu[(sub_w*2 + hf8)*AROW + px*4] = av;
        }
        // coords for next tap (other Cd buffer) overlap gather tail
        if (n < 8 && t < 128) coords_px(obase, h, n+1, t, Cdn + t*8);
        __syncthreads();

        // MFMA phase: A from LDS, B direct from L1-hot dwb2
        const unsigned short* As16 = (const unsigned short*)Asu;
        const unsigned short* dnb16 = (const unsigned short*)(dwb2 + n*2048);
        #pragma unroll
        for (int s=0;s<4;s++){
            h16x8 a  = *(const h16x8*)(As16 + (s*2+half)*(AROW*2) + (32*w + l31)*8);
            h16x8 b0 = *(const h16x8*)(dnb16 + ((s*2+half)*64 + l31)*8);
            h16x8 b1 = *(const h16x8*)(dnb16 + ((s*2+half)*64 + 32+l31)*8);
            acc0 = __builtin_amdgcn_mfma_f32_32x32x16_f16(a, b0, acc0, 0,0,0);
            acc1 = __builtin_amdgcn_mfma_f32_32x32x16_f16(a, b1, acc1, 0,0,0);
        }
        __syncthreads();
    }

    // epilogue: +db, ep[px][oc] u16 == dout2 row layout, straight copy out
    unsigned short* ep = (unsigned short*)smem_d;   // overlay (safe: barrier above)
    #pragma unroll
    for (int nt=0; nt<2; nt++){
        int oc = nt*32 + l31;
        float bias = db[oc];
        const f32x16& A = nt ? acc1 : acc0;
        #pragma unroll
        for (int rg=0; rg<4; rg++){
            int m0 = 32*w + 4*half + 8*rg;
            #pragma unroll
            for (int e=0;e<4;e++)
                ep[(m0+e)*64 + oc] = b16u(A[4*rg+e] + bias);
        }
    }
    __syncthreads();
    uint4* dst = (uint4*)((unsigned short*)dout2 + ((size_t)zb*128 + h)*(128*64));
    #pragma unroll
    for (int i=0;i<4;i++)
        dst[t + 256*i] = ((const uint4*)ep)[t + 256*i];
    #undef AROW
}

// ---------------------------------------------------------------------------
// K3b: 1x1 conv 256 -> 64 + cb + ReLU via f16 MFMA. grid (128 h, 4 b).
// A direct from dout2 (16-deep prefetch), B direct from L1-hot cwb2
// [kc][hf][oc][cl4]. Zero main-loop barriers.
// ---------------------------------------------------------------------------
__global__ __launch_bounds__(256,2) void k_combine_mfma(
    const f16* __restrict__ dout2,
    const unsigned* __restrict__ cwb2,  // [kc][hf][oc][cl4] u32
    const float* __restrict__ cb,
    float* __restrict__ out)
{
    int h = blockIdx.x, b = blockIdx.y;
    int t = threadIdx.x;
    int lane = t & 63, w = t >> 6, l31 = lane & 31, half = lane >> 5;

    __shared__ float ep2[64*132];   // 33.8 KB epilogue transpose

    f32x16 acc0, acc1;
    #pragma unroll
    for (int e=0;e<16;e++){ acc0[e]=0.f; acc1[e]=0.f; }

    const unsigned short* dbase0 = (const unsigned short*)dout2;
    const unsigned short* cb16 = (const unsigned short*)cwb2;
    size_t rowsel2 = ((size_t)b*128 + h)*128 + (32*w + l31);

    // issue all 16 A-fragment loads (16B each) up-front
    unsigned AV[64];
    #pragma unroll
    for (int kc=0; kc<16; kc++){
        *(uint4*)&AV[kc*4] = *(const uint4*)(
            dbase0 + (size_t)(kc>>2)*(4*HW*64) + rowsel2*64 + (kc&3)*16 + half*8);
    }
    #pragma unroll
    for (int kc=0; kc<16; kc++){
        h16x8 a  = __builtin_bit_cast(h16x8, *(uint4*)&AV[kc*4]);
        h16x8 b0 = *(const h16x8*)(cb16 + ((kc*2+half)*64 + l31)*8);
        h16x8 b1 = *(const h16x8*)(cb16 + ((kc*2+half)*64 + 32+l31)*8);
        acc0 = __builtin_amdgcn_mfma_f32_32x32x16_f16(a, b0, acc0, 0,0,0);
        acc1 = __builtin_amdgcn_mfma_f32_32x32x16_f16(a, b1, acc1, 0,0,0);
    }

    #pragma unroll
    for (int nt=0; nt<2; nt++){
        int oc = nt*32 + l31;
        float bias = cb[oc];
        const f32x16& A = nt ? acc1 : acc0;
        #pragma unroll
        for (int rg=0; rg<4; rg++){
            int m0 = 32*w + 4*half + 8*rg;
            #pragma unroll
            for (int e=0;e<4;e++)
                ep2[oc*132 + m0+e] = fmaxf(A[4*rg+e] + bias, 0.f);
        }
    }
    __syncthreads();
    for (int i=t; i<2048; i+=256){
        int oc = i>>5, sg = i&31;
        *(uint4*)&out[(((size_t)b*64+oc)*128 + h)*128 + sg*4] = *(const uint4*)&ep2[oc*132 + sg*4];
    }
}

extern "C" void kernel_launch(void* const* d_in, const int* in_sizes, int n_in,
                              void* d_out, int out_size, void* d_ws, size_t ws_size,
                              hipStream_t stream) {
    const float* x  = (const float*)d_in[0];
    const float* w1 = (const float*)d_in[1];
    const float* b1 = (const float*)d_in[2];
    const float* w2 = (const float*)d_in[3];
    const float* b2 = (const float*)d_in[4];
    const float* w3 = (const float*)d_in[5];
    const float* b3 = (const float*)d_in[6];
    const float* w4 = (const float*)d_in[7];
    const float* b4 = (const float*)d_in[8];
    const float* pw = (const float*)d_in[9];
    const float* pb = (const float*)d_in[10];
    const float* dw = (const float*)d_in[11];
    const float* db = (const float*)d_in[12];
    const float* cw = (const float*)d_in[13];
    const float* cb = (const float*)d_in[14];
    float* out = (float*)d_out;

    f16* feats2 = (f16*)d_ws;                               // 34.6 MB
    f16* offs   = feats2 + (size_t)16*FSL;                  // 9.4 MB
    f16* region2 = offs + (size_t)16*18*HW;
    f16* dout2  = region2;                                  // 33.55 MB
    unsigned* xt  = (unsigned*)region2;                     // 21.2 MB (dead before dout2)
    unsigned* wbt = xt + (size_t)4*8*XTD*XTD*8;             // 0.59 MB (dead before dout2)
    unsigned* dwb2 = (unsigned*)(dout2 + (size_t)16*128*128*64);  // 73.7 KB
    unsigned* cwb2 = dwb2 + 18432;                          // 32.8 KB
    unsigned* pwb  = cwb2 + 8192;                           // 36.9 KB

    k_prep        <<<dim3(1740),    256, 0, stream>>>(w1,w2,w3,w4, dw, cw, pw,
                                                      (uint4*)xt, wbt, dwb2, cwb2, pwb);
    k_xprep       <<<dim3(128,4),   256, 0, stream>>>(x, xt);
    k_branch_mfma <<<dim3(1024),    256, 0, stream>>>(xt, wbt, b1,b2,b3,b4, feats2);
    k_offset_mfma <<<dim3(2048),    256, 0, stream>>>(feats2, pwb, pb, offs);
    k_deform_mfma <<<dim3(2048),    256, 0, stream>>>(feats2, offs, dwb2, db, dout2);
    k_combine_mfma<<<dim3(128,4),   256, 0, stream>>>(dout2, cwb2, cb, out);
}

// Round 7
// 291.774 us; speedup vs baseline: 1.0608x; 1.0322x over previous
//
#include <hip/hip_runtime.h>
#include <hip/hip_fp16.h>

#define H 128
#define W 128
#define CIN 128
#define COUT 64
#define HW (H*W)
#define XW 130                    // padded spatial dim (y,x in [0,129])
#define FSL (XW*XW*64)            // feats2 elems per zb slice (NHWC f16)
#define XTD 144                   // xt padded dim

typedef __half f16;
typedef __attribute__((ext_vector_type(8)))  _Float16 h16x8;
typedef __attribute__((ext_vector_type(16))) float f32x16;

__device__ __forceinline__ float b2f(f16 v){ return __half2float(v); }
__device__ __forceinline__ f16  f2b(float v){ return __float2half_rn(v); }
__device__ __forceinline__ unsigned pack2(float a, float b){
    unsigned short ua = __builtin_bit_cast(unsigned short, f2b(a));
    unsigned short ub = __builtin_bit_cast(unsigned short, f2b(b));
    return (unsigned)ua | ((unsigned)ub << 16);
}
__device__ __forceinline__ unsigned short b16u(float v){
    return __builtin_bit_cast(unsigned short, f2b(v));
}
__device__ __forceinline__ __half2 uh2(unsigned u){
    return __builtin_bit_cast(__half2, u);
}
__device__ __forceinline__ unsigned h2u(__half2 v){
    return __builtin_bit_cast(unsigned, v);
}
__device__ __forceinline__ unsigned bcasth2(float v){
    __half h = __float2half_rn(v);
    return h2u(__halves2half2(h, h));
}
// async global->LDS, 16B per lane; lds dest must be linear in lane id
__device__ __forceinline__ void gld16(const void* g, void* l){
    __builtin_amdgcn_global_load_lds(
        (const __attribute__((address_space(1))) void*)g,
        (__attribute__((address_space(3))) void*)l, 16, 0, 0);
}

// ---------------------------------------------------------------------------
// k_prep: [0,1024) zero xt2; [1024,1600) wbt; [1600,1672) dwb2;
//         [1672,1704) cwb2; [1704,1740) pwb      (all tables packed f16 pairs)
// dwb2 [n][oc][cp32] (R3 staged-B layout); cwb2 [kc][hf][oc][cl4] (direct-B).
// ---------------------------------------------------------------------------
__global__ __launch_bounds__(256) void k_prep(
    const float* __restrict__ w1, const float* __restrict__ w2,
    const float* __restrict__ w3, const float* __restrict__ w4,
    const float* __restrict__ dw, const float* __restrict__ cw,
    const float* __restrict__ pw,
    uint4* __restrict__ xt4, unsigned* __restrict__ wbt,
    unsigned* __restrict__ dwb2, unsigned* __restrict__ cwb2,
    unsigned* __restrict__ pwb)
{
    int bid = blockIdx.x;
    int t = threadIdx.x;
    if (bid < 1024){
        const int n4 = (4*XTD*XTD*64)/4;        // 1327104
        for (int i = bid*256 + t; i < n4; i += 1024*256)
            xt4[i] = make_uint4(0,0,0,0);
    } else if (bid < 1600){
        int tid = (bid-1024)*256 + t;            // 147456 = 4*8*9*64*8
        int cpl = tid & 7;
        int oc  = (tid >> 3) & 63;
        int tap = (tid >> 9) % 9;
        int cg  = (tid / 4608) & 7;
        int d   = tid / 36864;
        const float* wt = (d==0)?w1:(d==1)?w2:(d==2)?w3:w4;
        int c = cg*8 + cpl;
        wbt[tid] = pack2(wt[((size_t)oc*CIN + 2*c  )*9 + tap],
                         wt[((size_t)oc*CIN + 2*c+1)*9 + tap]);
    } else if (bid < 1672){
        int i = (bid-1600)*256 + t;              // 18432: dwb2[n][oc][cp32]
        int n = i>>11, oc = (i>>5)&63, cp = i&31;
        dwb2[i] = pack2(dw[((size_t)oc*64 + 2*cp  )*9 + n],
                        dw[((size_t)oc*64 + 2*cp+1)*9 + n]);
    } else if (bid < 1704){
        int i = (bid-1672)*256 + t;              // 8192: cwb2[kc][hf][oc][cl4]
        int kc = i>>9;
        int hf = (i>>8)&1;
        int oc = (i>>2)&63;
        int cl = i&3;
        int cp = kc*8 + hf*4 + cl;               // channel-pair 0..127
        cwb2[i] = pack2(cw[(size_t)oc*256 + 2*cp], cw[(size_t)oc*256 + 2*cp+1]);
    } else {
        int i = (bid-1704)*256 + t;              // 9216
        int cl = i & 3, oc = (i>>2)&31, hf = (i>>7)&1, cq = (i>>8)&3, tap = i>>10;
        int c = cq*16 + hf*8 + cl*2;
        unsigned v = 0u;
        if (oc < 18)
            v = pack2(pw[((size_t)oc*64 + c  )*9 + tap],
                      pw[((size_t)oc*64 + c+1)*9 + tap]);
        pwb[i] = v;
    }
}

// ---------------------------------------------------------------------------
// xprep: xt2[b][cg 8][y+8][col+8][cpl 8] u32 (interior). grid (128 y, 4 b).
// ---------------------------------------------------------------------------
__global__ __launch_bounds__(256) void k_xprep(
    const float* __restrict__ x, unsigned* __restrict__ xt)
{
    int y = blockIdx.x, b = blockIdx.y;
    int t = threadIdx.x;
    __shared__ float xsm[64*131];
    for (int ci0 = 0; ci0 < 128; ci0 += 64){
        for (int i=0;i<32;i++){
            int idx = t + 256*i;
            int col = idx & 127, ci = idx >> 7;
            xsm[ci*131 + col] = x[(((size_t)b*CIN + ci0+ci)*H + y)*W + col];
        }
        __syncthreads();
        for (int i=0;i<16;i++){
            int idx = t + 256*i;
            int cpg = idx & 31, col = idx >> 5;
            int cgg = (ci0 >> 4) + (cpg >> 3);
            int cpl = cpg & 7;
            unsigned u = pack2(xsm[(2*cpg)*131 + col], xsm[(2*cpg+1)*131 + col]);
            xt[((((size_t)b*8 + cgg)*XTD + y+8)*XTD + col+8)*8 + cpl] = u;
        }
        __syncthreads();
    }
}

// ---------------------------------------------------------------------------
// K1: dilated 3x3 conv via f16 MFMA implicit GEMM. grid 1024 1-D, XCD swizzle.
// (R4 structure: linear LDS + global_load_lds staging, conflict-free reads)
// ---------------------------------------------------------------------------
__global__ __launch_bounds__(256,3) void k_branch_mfma(
    const unsigned* __restrict__ xt, const unsigned* __restrict__ wbt,
    const float* __restrict__ b1, const float* __restrict__ b2,
    const float* __restrict__ b3, const float* __restrict__ b4,
    f16* __restrict__ feats2)
{
    int bid = blockIdx.x;
    int xcd = bid & 7;
    int j   = bid >> 3;
    int zb  = xcd + 8*(j & 1);
    int hp  = j >> 1;
    int d = zb >> 2, b = zb & 3;
    int dil = 2*d + 1;
    int h0 = hp*2;
    const float* bs = (d==0)?b1:(d==1)?b2:(d==2)?b3:b4;
    const float scale = (float)dil;

    __shared__ unsigned smem[6912 + 4608];     // As 27KB + Bs 18KB = 45KB
    unsigned* As = smem;
    unsigned* Bs = smem + 6912;
    const unsigned short* As16 = (const unsigned short*)As;
    const unsigned short* Bs16 = (const unsigned short*)Bs;

    int t = threadIdx.x;
    int lane = t & 63;
    int w = t >> 6;
    int l31 = lane & 31;
    int half = lane >> 5;

    f16* fb = feats2 + (size_t)zb*FSL;
    if (t < 32){
        int yy = h0 + 1 + (t>>4);
        int side = (t>>3)&1;
        int q = t & 7;
        uint4 z = make_uint4(0,0,0,0);
        *(uint4*)((unsigned short*)fb + ((size_t)yy*XW + side*129)*64 + q*8) = z;
    }
    if (hp == 0){
        uint4 z = make_uint4(0,0,0,0);
        for (int i=t; i<2080; i+=256){
            int row = i / 1040;
            int r = i % 1040;
            int xx = r >> 3, q = r & 7;
            *(uint4*)((unsigned short*)fb + ((size_t)(row*129)*XW + xx)*64 + q*8) = z;
        }
    }

    f32x16 acc[2][2];
    #pragma unroll
    for (int i=0;i<2;i++)
      #pragma unroll
      for (int jj=0;jj<2;jj++)
        #pragma unroll
        for (int e=0;e<16;e++) acc[i][jj][e] = 0.f;

    const unsigned* xtb_b = xt + (size_t)b*8*XTD*XTD*8;
    int r = w >> 1;
    int pxb = (w & 1) * 64;

    for (int cg=0; cg<8; cg++){
        const unsigned* xs_cg = xtb_b + (size_t)cg*XTD*XTD*8;
        #pragma unroll
        for (int i=0;i<7;i++){
            int idx4 = t + 256*i;
            if (idx4 < 1728){
                int row6 = idx4 / 288;
                int rem  = idx4 - row6*288;
                int hf   = rem / 144;
                int s    = rem - hf*144;
                int ky = row6 >> 1, rr = row6 & 1;
                int yy = h0 + rr + (ky-1)*dil + 8;
                gld16(xs_cg + ((size_t)yy*XTD + (s + 8 - dil))*8 + hf*4,
                      &As[idx4*4]);
            }
        }
        const unsigned* wb_cg = wbt + ((size_t)d*8 + cg)*4608;
        #pragma unroll
        for (int i=0;i<5;i++){
            int idx4 = t + 256*i;
            if (idx4 < 1152){
                int tap = idx4 >> 7;
                int hf  = (idx4 >> 6) & 1;
                int oc  = idx4 & 63;
                gld16(wb_cg + ((size_t)tap*64 + oc)*8 + hf*4,
                      &Bs[idx4*4]);
            }
        }
        __syncthreads();
        #pragma unroll
        for (int tap=0; tap<9; tap++){
            int ky = tap/3, kx = tap%3;
            int arow = ((ky*2 + r)*2 + half)*144;
            int brow = (tap*2 + half)*64;
            h16x8 a0  = *(const h16x8*)(As16 + (arow + pxb      + l31 + kx*dil)*8);
            h16x8 a1  = *(const h16x8*)(As16 + (arow + pxb + 32 + l31 + kx*dil)*8);
            h16x8 bb0 = *(const h16x8*)(Bs16 + (brow      + l31)*8);
            h16x8 bb1 = *(const h16x8*)(Bs16 + (brow + 32 + l31)*8);
            acc[0][0] = __builtin_amdgcn_mfma_f32_32x32x16_f16(a0, bb0, acc[0][0], 0,0,0);
            acc[0][1] = __builtin_amdgcn_mfma_f32_32x32x16_f16(a0, bb1, acc[0][1], 0,0,0);
            acc[1][0] = __builtin_amdgcn_mfma_f32_32x32x16_f16(a1, bb0, acc[1][0], 0,0,0);
            acc[1][1] = __builtin_amdgcn_mfma_f32_32x32x16_f16(a1, bb1, acc[1][1], 0,0,0);
        }
        __syncthreads();
    }

    unsigned short* ep = (unsigned short*)smem;   // 32KB overlay
    float bias0 = bs[l31], bias1 = bs[32 + l31];
    #pragma unroll
    for (int i=0;i<2;i++){
      #pragma unroll
      for (int jj=0;jj<2;jj++){
        int oc = jj*32 + l31;
        float bj = jj ? bias1 : bias0;
        #pragma unroll
        for (int rg=0; rg<4; rg++){
            int m0 = 64*w + 32*i + 8*rg + 4*half;
            #pragma unroll
            for (int e=0;e<4;e++)
                ep[(m0+e)*64 + oc] = b16u((acc[i][jj][4*rg+e] + bj)*scale);
        }
      }
    }
    __syncthreads();
    {
        int row = t >> 7, pxm = t & 127;
        unsigned short* drow = (unsigned short*)fb + ((size_t)(h0+1+row)*XW + pxm + 1)*64;
        const unsigned short* srow = ep + t*64;
        #pragma unroll
        for (int q=0;q<8;q++)
            *(uint4*)(drow + q*8) = *(const uint4*)(srow + q*8);
    }
}

// ---------------------------------------------------------------------------
// K2: 3x3 conv 64 -> 18 (offsets) via f16 MFMA, XCD swizzle.
// ---------------------------------------------------------------------------
__global__ __launch_bounds__(256,2) void k_offset_mfma(
    const f16* __restrict__ feats2,
    const unsigned* __restrict__ pwb,   // [tap][cq][hf][oc32][cl4] u32
    const float* __restrict__ pb,
    f16* __restrict__ offs)
{
    int bid = blockIdx.x;
    int xcd  = bid & 7;
    int h    = (bid >> 3) & 127;
    int pass = bid >> 10;
    int zb   = xcd + 8*pass;

    int t = threadIdx.x;
    int lane = t & 63, w = t >> 6;
    int l31 = lane & 31, half = lane >> 5;

    __shared__ unsigned short xs[3*132*68];   // 53.9 KB

    const unsigned short* fin = (const unsigned short*)(feats2 + (size_t)zb*FSL);
    for (int i=t; i<3120; i+=256){
        int row = i / 1040;
        int r   = i % 1040;
        int col = r >> 3, q = r & 7;
        uint4 v = *(const uint4*)(fin + ((size_t)(h+row)*XW + col)*64 + q*8);
        *(uint4*)&xs[(row*132 + col)*68 + q*8] = v;
    }
    __syncthreads();

    f32x16 acc;
    #pragma unroll
    for (int e=0;e<16;e++) acc[e] = 0.f;

    int pxw = 32*w + l31;
    #pragma unroll
    for (int tap=0; tap<9; tap++){
        int ky = tap/3, kx = tap%3;
        const unsigned short* arow = &xs[(ky*132 + pxw + kx)*68 + half*8];
        const unsigned* brow = pwb + (((size_t)tap*4)*2 + half)*128 + l31*4;
        #pragma unroll
        for (int cq=0; cq<4; cq++){
            h16x8 a  = *(const h16x8*)(arow + cq*16);
            h16x8 b0 = *(const h16x8*)(brow + cq*256);
            acc = __builtin_amdgcn_mfma_f32_32x32x16_f16(a, b0, acc, 0,0,0);
        }
    }
    __syncthreads();

    unsigned short* ep = (unsigned short*)xs;   // [oc 18][132 pad]
    if (l31 < 18){
        float bias = pb[l31];
        #pragma unroll
        for (int rg=0; rg<4; rg++){
            int m0 = 32*w + 4*half + 8*rg;
            #pragma unroll
            for (int e=0;e<4;e++)
                ep[l31*132 + m0+e] = b16u(acc[4*rg+e] + bias);
        }
    }
    __syncthreads();
    unsigned short* obase = (unsigned short*)(offs + (size_t)zb*18*HW) ;
    for (int i=t; i<288; i+=256){
        int oc = i >> 4, sg = i & 15;
        *(uint4*)(obase + (size_t)oc*HW + h*W + sg*8) = *(const uint4*)(ep + oc*132 + sg*8);
    }
}

// ---------------------------------------------------------------------------
// K3a: deform sampling + dw einsum via f16 MFMA — R3 proven structure
// (staged B in LDS, single coords buffer, 3 barriers/tap, (256,4)) with an
// explicit 2-deep NAMED-REGISTER gather pipeline: slot s+1's coords+corners
// load while slot s interpolates. No arrays -> no scratch demotion.
// grid 2048 1-D, XCD swizzle.
// ---------------------------------------------------------------------------
__global__ __launch_bounds__(256,4) void k_deform_mfma(
    const f16* __restrict__ feats2,
    const f16* __restrict__ offs,
    const unsigned* __restrict__ dwb2,  // [n][oc][cp32] u32
    const float* __restrict__ db,
    f16* __restrict__ dout2)
{
    int bid = blockIdx.x;
    int xcd  = bid & 7;
    int h    = (bid >> 3) & 127;
    int pass = bid >> 10;
    int zb   = xcd + 8*pass;

    int t = threadIdx.x;
    int lane = t & 63, w = t >> 6;
    int l31 = lane & 31, half = lane >> 5;
    int pxg = t >> 3;                 // 0..31, pixel group (gather phase)
    int cq  = t & 7;                  // which 8-ch slice of the 64-ch line
    int sub_w = cq >> 1;              // A-frag sub (0..3)
    int hf8   = cq & 1;               // A-frag half (0..1)

    #define AROW 516                   // u32 row stride (8 rows)
    __shared__ unsigned smem_d[8*AROW + 2304 + 1024];  // A 16.5KB + B 9.2KB + coords 4KB
    unsigned* Asu = smem_d;
    unsigned* Bsu = smem_d + 8*AROW;
    unsigned* Cd  = smem_d + 8*AROW + 2304;   // [px 128][8]

    const f16* obase = offs + (size_t)zb*18*HW + h*W;
    const unsigned short* fbase = (const unsigned short*)(feats2 + (size_t)zb*FSL);

    f32x16 acc0, acc1;
    #pragma unroll
    for (int e=0;e<16;e++){ acc0[e]=0.f; acc1[e]=0.f; }

#define CLOAD(S, C0, C1) { \
    const unsigned* cp_ = Cd + ((S)*32 + pxg)*8; \
    C0 = *(const uint4*)cp_; \
    C1 = *(const uint4*)(cp_ + 4); }
#define GLOAD(C1, LT, LB, RT, RB) { \
    int dxo_ = (int)(C1).y, dyo_ = (int)(C1).z; \
    const unsigned short* fc_ = fbase + (int)(C1).x + cq*8; \
    LT = *(const uint4*)(fc_); \
    LB = *(const uint4*)(fc_ + dxo_); \
    RT = *(const uint4*)(fc_ + dyo_); \
    RB = *(const uint4*)(fc_ + dyo_ + dxo_); }
#define INTERP(S, C0, LT, LB, RT, RB) { \
    __half2 wlt_ = uh2((C0).x), wlb_ = uh2((C0).y); \
    __half2 wrt_ = uh2((C0).z), wrb_ = uh2((C0).w); \
    unsigned p0_,p1_,p2_,p3_; \
    { __half2 r_ = __hmul2(wlt_, uh2((LT).x)); r_ = __hfma2(wlb_, uh2((LB).x), r_); \
      r_ = __hfma2(wrt_, uh2((RT).x), r_); r_ = __hfma2(wrb_, uh2((RB).x), r_); p0_ = h2u(r_); } \
    { __half2 r_ = __hmul2(wlt_, uh2((LT).y)); r_ = __hfma2(wlb_, uh2((LB).y), r_); \
      r_ = __hfma2(wrt_, uh2((RT).y), r_); r_ = __hfma2(wrb_, uh2((RB).y), r_); p1_ = h2u(r_); } \
    { __half2 r_ = __hmul2(wlt_, uh2((LT).z)); r_ = __hfma2(wlb_, uh2((LB).z), r_); \
      r_ = __hfma2(wrt_, uh2((RT).z), r_); r_ = __hfma2(wrb_, uh2((RB).z), r_); p2_ = h2u(r_); } \
    { __half2 r_ = __hmul2(wlt_, uh2((LT).w)); r_ = __hfma2(wlb_, uh2((LB).w), r_); \
      r_ = __hfma2(wrt_, uh2((RT).w), r_); r_ = __hfma2(wrb_, uh2((RB).w), r_); p3_ = h2u(r_); } \
    uint4 av_; av_.x=p0_; av_.y=p1_; av_.z=p2_; av_.w=p3_; \
    *(uint4*)&Asu[(sub_w*2 + hf8)*AROW + ((S)*32 + pxg)*4] = av_; }

    for (int n=0; n<9; n++){
        // stage B for this n
        const uint4* dsrc = (const uint4*)(dwb2 + n*2048);
        #pragma unroll
        for (int i=0;i<2;i++){
            int j = t + 256*i;
            int idx4 = j*4;
            int oc = idx4 >> 5, cp = idx4 & 31;
            *(uint4*)&Bsu[oc*36 + cp] = dsrc[j];
        }
        // cooperative coords: thread t<128 computes pixel t once
        if (t < 128){
            float offy = b2f(obase[n*HW + t]);
            float offx = b2f(obase[(n+9)*HW + t]);
            float py  = (float)(h + n/3) + offy;
            float pxf = (float)(t + n%3) + offx;
            float fy = floorf(py), fx = floorf(pxf);
            float lty = fminf(fmaxf(fy,     0.f),129.f);
            float ltx = fminf(fmaxf(fx,     0.f),129.f);
            float rby = fminf(fmaxf(fy+1.f, 0.f),129.f);
            float rbx = fminf(fmaxf(fx+1.f, 0.f),129.f);
            float pyc = fminf(fmaxf(py,     0.f),129.f);
            float pxc = fminf(fmaxf(pxf,    0.f),129.f);
            float ay = 1.f + (lty-pyc), by = 1.f - (rby-pyc);
            float ax = 1.f + (ltx-pxc), bx = 1.f - (rbx-pxc);
            unsigned* cp = &Cd[t*8];
            cp[0] = bcasth2(ay*ax);
            cp[1] = bcasth2(ay*bx);
            cp[2] = bcasth2(by*ax);
            cp[3] = bcasth2(by*bx);
            cp[4] = (unsigned)(((int)lty*XW + (int)ltx)*64);
            cp[5] = (unsigned)(((int)rbx - (int)ltx)*64);
            cp[6] = (unsigned)(((int)rby - (int)lty)*XW*64);
        }
        __syncthreads();

        // 2-deep pipelined gather: named register sets a/b, constant indices
        {
            uint4 c0a, c1a, c0b, c1b;
            uint4 LTa, LBa, RTa, RBa;
            uint4 LTb, LBb, RTb, RBb;
            CLOAD(0, c0a, c1a); GLOAD(c1a, LTa, LBa, RTa, RBa);
            CLOAD(1, c0b, c1b); GLOAD(c1b, LTb, LBb, RTb, RBb);
            INTERP(0, c0a, LTa, LBa, RTa, RBa);
            CLOAD(2, c0a, c1a); GLOAD(c1a, LTa, LBa, RTa, RBa);
            INTERP(1, c0b, LTb, LBb, RTb, RBb);
            CLOAD(3, c0b, c1b); GLOAD(c1b, LTb, LBb, RTb, RBb);
            INTERP(2, c0a, LTa, LBa, RTa, RBa);
            INTERP(3, c0b, LTb, LBb, RTb, RBb);
        }
        __syncthreads();

        const unsigned short* As16 = (const unsigned short*)Asu;
        const unsigned short* Bs16 = (const unsigned short*)Bsu;
        #pragma unroll
        for (int s=0;s<4;s++){
            h16x8 a  = *(const h16x8*)(As16 + (s*2+half)*(AROW*2) + (32*w + l31)*8);
            h16x8 b0 = *(const h16x8*)(Bs16 + (l31*36 + s*8 + half*4)*2);
            h16x8 b1 = *(const h16x8*)(Bs16 + ((32+l31)*36 + s*8 + half*4)*2);
            acc0 = __builtin_amdgcn_mfma_f32_32x32x16_f16(a, b0, acc0, 0,0,0);
            acc1 = __builtin_amdgcn_mfma_f32_32x32x16_f16(a, b1, acc1, 0,0,0);
        }
        __syncthreads();
    }
#undef CLOAD
#undef GLOAD
#undef INTERP

    // epilogue: +db, ep[px][oc] u16 == dout2 row layout, straight copy out
    unsigned short* ep = (unsigned short*)smem_d;   // overlay (safe: barrier above)
    #pragma unroll
    for (int nt=0; nt<2; nt++){
        int oc = nt*32 + l31;
        float bias = db[oc];
        const f32x16& A = nt ? acc1 : acc0;
        #pragma unroll
        for (int rg=0; rg<4; rg++){
            int m0 = 32*w + 4*half + 8*rg;
            #pragma unroll
            for (int e=0;e<4;e++)
                ep[(m0+e)*64 + oc] = b16u(A[4*rg+e] + bias);
        }
    }
    __syncthreads();
    uint4* dst = (uint4*)((unsigned short*)dout2 + ((size_t)zb*128 + h)*(128*64));
    #pragma unroll
    for (int i=0;i<4;i++)
        dst[t + 256*i] = ((const uint4*)ep)[t + 256*i];
    #undef AROW
}

// ---------------------------------------------------------------------------
// K3b: 1x1 conv 256 -> 64 + cb + ReLU via f16 MFMA. grid (128 h, 4 b).
// A direct from dout2 (16-deep prefetch), B direct from L1-hot cwb2
// [kc][hf][oc][cl4]. Zero main-loop barriers.
// ---------------------------------------------------------------------------
__global__ __launch_bounds__(256,2) void k_combine_mfma(
    const f16* __restrict__ dout2,
    const unsigned* __restrict__ cwb2,  // [kc][hf][oc][cl4] u32
    const float* __restrict__ cb,
    float* __restrict__ out)
{
    int h = blockIdx.x, b = blockIdx.y;
    int t = threadIdx.x;
    int lane = t & 63, w = t >> 6, l31 = lane & 31, half = lane >> 5;

    __shared__ float ep2[64*132];   // 33.8 KB epilogue transpose

    f32x16 acc0, acc1;
    #pragma unroll
    for (int e=0;e<16;e++){ acc0[e]=0.f; acc1[e]=0.f; }

    const unsigned short* dbase0 = (const unsigned short*)dout2;
    const unsigned short* cb16 = (const unsigned short*)cwb2;
    size_t rowsel2 = ((size_t)b*128 + h)*128 + (32*w + l31);

    // issue all 16 A-fragment loads (16B each) up-front
    unsigned AV[64];
    #pragma unroll
    for (int kc=0; kc<16; kc++){
        *(uint4*)&AV[kc*4] = *(const uint4*)(
            dbase0 + (size_t)(kc>>2)*(4*HW*64) + rowsel2*64 + (kc&3)*16 + half*8);
    }
    #pragma unroll
    for (int kc=0; kc<16; kc++){
        h16x8 a  = __builtin_bit_cast(h16x8, *(uint4*)&AV[kc*4]);
        h16x8 b0 = *(const h16x8*)(cb16 + ((kc*2+half)*64 + l31)*8);
        h16x8 b1 = *(const h16x8*)(cb16 + ((kc*2+half)*64 + 32+l31)*8);
        acc0 = __builtin_amdgcn_mfma_f32_32x32x16_f16(a, b0, acc0, 0,0,0);
        acc1 = __builtin_amdgcn_mfma_f32_32x32x16_f16(a, b1, acc1, 0,0,0);
    }

    #pragma unroll
    for (int nt=0; nt<2; nt++){
        int oc = nt*32 + l31;
        float bias = cb[oc];
        const f32x16& A = nt ? acc1 : acc0;
        #pragma unroll
        for (int rg=0; rg<4; rg++){
            int m0 = 32*w + 4*half + 8*rg;
            #pragma unroll
            for (int e=0;e<4;e++)
                ep2[oc*132 + m0+e] = fmaxf(A[4*rg+e] + bias, 0.f);
        }
    }
    __syncthreads();
    for (int i=t; i<2048; i+=256){
        int oc = i>>5, sg = i&31;
        *(uint4*)&out[(((size_t)b*64+oc)*128 + h)*128 + sg*4] = *(const uint4*)&ep2[oc*132 + sg*4];
    }
}

extern "C" void kernel_launch(void* const* d_in, const int* in_sizes, int n_in,
                              void* d_out, int out_size, void* d_ws, size_t ws_size,
                              hipStream_t stream) {
    const float* x  = (const float*)d_in[0];
    const float* w1 = (const float*)d_in[1];
    const float* b1 = (const float*)d_in[2];
    const float* w2 = (const float*)d_in[3];
    const float* b2 = (const float*)d_in[4];
    const float* w3 = (const float*)d_in[5];
    const float* b3 = (const float*)d_in[6];
    const float* w4 = (const float*)d_in[7];
    const float* b4 = (const float*)d_in[8];
    const float* pw = (const float*)d_in[9];
    const float* pb = (const float*)d_in[10];
    const float* dw = (const float*)d_in[11];
    const float* db = (const float*)d_in[12];
    const float* cw = (const float*)d_in[13];
    const float* cb = (const float*)d_in[14];
    float* out = (float*)d_out;

    f16* feats2 = (f16*)d_ws;                               // 34.6 MB
    f16* offs   = feats2 + (size_t)16*FSL;                  // 9.4 MB
    f16* region2 = offs + (size_t)16*18*HW;
    f16* dout2  = region2;                                  // 33.55 MB
    unsigned* xt  = (unsigned*)region2;                     // 21.2 MB (dead before dout2)
    unsigned* wbt = xt + (size_t)4*8*XTD*XTD*8;             // 0.59 MB (dead before dout2)
    unsigned* dwb2 = (unsigned*)(dout2 + (size_t)16*128*128*64);  // 73.7 KB
    unsigned* cwb2 = dwb2 + 18432;                          // 32.8 KB
    unsigned* pwb  = cwb2 + 8192;                           // 36.9 KB

    k_prep        <<<dim3(1740),    256, 0, stream>>>(w1,w2,w3,w4, dw, cw, pw,
                                                      (uint4*)xt, wbt, dwb2, cwb2, pwb);
    k_xprep       <<<dim3(128,4),   256, 0, stream>>>(x, xt);
    k_branch_mfma <<<dim3(1024),    256, 0, stream>>>(xt, wbt, b1,b2,b3,b4, feats2);
    k_offset_mfma <<<dim3(2048),    256, 0, stream>>>(feats2, pwb, pb, offs);
    k_deform_mfma <<<dim3(2048),    256, 0, stream>>>(feats2, offs, dwb2, db, dout2);
    k_combine_mfma<<<dim3(128,4),   256, 0, stream>>>(dout2, cwb2, cb, out);
}

// Round 8
// 289.428 us; speedup vs baseline: 1.0694x; 1.0081x over previous
//
#include <hip/hip_runtime.h>
#include <hip/hip_fp16.h>

#define H 128
#define W 128
#define CIN 128
#define COUT 64
#define HW (H*W)
#define XW 130                    // padded spatial dim (y,x in [0,129])
#define FSL (XW*XW*64)            // feats2 elems per zb slice (NHWC f16)
#define XTD 144                   // xt padded dim

typedef __half f16;
typedef __attribute__((ext_vector_type(8)))  _Float16 h16x8;
typedef __attribute__((ext_vector_type(16))) float f32x16;

__device__ __forceinline__ float b2f(f16 v){ return __half2float(v); }
__device__ __forceinline__ f16  f2b(float v){ return __float2half_rn(v); }
__device__ __forceinline__ unsigned pack2(float a, float b){
    unsigned short ua = __builtin_bit_cast(unsigned short, f2b(a));
    unsigned short ub = __builtin_bit_cast(unsigned short, f2b(b));
    return (unsigned)ua | ((unsigned)ub << 16);
}
__device__ __forceinline__ unsigned short b16u(float v){
    return __builtin_bit_cast(unsigned short, f2b(v));
}
__device__ __forceinline__ __half2 uh2(unsigned u){
    return __builtin_bit_cast(__half2, u);
}
__device__ __forceinline__ unsigned h2u(__half2 v){
    return __builtin_bit_cast(unsigned, v);
}
__device__ __forceinline__ unsigned bcasth2(float v){
    __half h = __float2half_rn(v);
    return h2u(__halves2half2(h, h));
}
// async global->LDS, 16B per lane; lds dest must be linear in lane id
__device__ __forceinline__ void gld16(const void* g, void* l){
    __builtin_amdgcn_global_load_lds(
        (const __attribute__((address_space(1))) void*)g,
        (__attribute__((address_space(3))) void*)l, 16, 0, 0);
}

// ---------------------------------------------------------------------------
// k_prep: [0,1024) zero xt2; [1024,1600) wbt; [1600,1672) dwb2;
//         [1672,1704) cwb2; [1704,1740) pwb      (all tables packed f16 pairs)
// dwb2 [n][oc][cp32] (R3 staged-B layout); cwb2 [kc][hf][oc][cl4] (direct-B).
// ---------------------------------------------------------------------------
__global__ __launch_bounds__(256) void k_prep(
    const float* __restrict__ w1, const float* __restrict__ w2,
    const float* __restrict__ w3, const float* __restrict__ w4,
    const float* __restrict__ dw, const float* __restrict__ cw,
    const float* __restrict__ pw,
    uint4* __restrict__ xt4, unsigned* __restrict__ wbt,
    unsigned* __restrict__ dwb2, unsigned* __restrict__ cwb2,
    unsigned* __restrict__ pwb)
{
    int bid = blockIdx.x;
    int t = threadIdx.x;
    if (bid < 1024){
        const int n4 = (4*XTD*XTD*64)/4;        // 1327104
        for (int i = bid*256 + t; i < n4; i += 1024*256)
            xt4[i] = make_uint4(0,0,0,0);
    } else if (bid < 1600){
        int tid = (bid-1024)*256 + t;            // 147456 = 4*8*9*64*8
        int cpl = tid & 7;
        int oc  = (tid >> 3) & 63;
        int tap = (tid >> 9) % 9;
        int cg  = (tid / 4608) & 7;
        int d   = tid / 36864;
        const float* wt = (d==0)?w1:(d==1)?w2:(d==2)?w3:w4;
        int c = cg*8 + cpl;
        wbt[tid] = pack2(wt[((size_t)oc*CIN + 2*c  )*9 + tap],
                         wt[((size_t)oc*CIN + 2*c+1)*9 + tap]);
    } else if (bid < 1672){
        int i = (bid-1600)*256 + t;              // 18432: dwb2[n][oc][cp32]
        int n = i>>11, oc = (i>>5)&63, cp = i&31;
        dwb2[i] = pack2(dw[((size_t)oc*64 + 2*cp  )*9 + n],
                        dw[((size_t)oc*64 + 2*cp+1)*9 + n]);
    } else if (bid < 1704){
        int i = (bid-1672)*256 + t;              // 8192: cwb2[kc][hf][oc][cl4]
        int kc = i>>9;
        int hf = (i>>8)&1;
        int oc = (i>>2)&63;
        int cl = i&3;
        int cp = kc*8 + hf*4 + cl;               // channel-pair 0..127
        cwb2[i] = pack2(cw[(size_t)oc*256 + 2*cp], cw[(size_t)oc*256 + 2*cp+1]);
    } else {
        int i = (bid-1704)*256 + t;              // 9216
        int cl = i & 3, oc = (i>>2)&31, hf = (i>>7)&1, cq = (i>>8)&3, tap = i>>10;
        int c = cq*16 + hf*8 + cl*2;
        unsigned v = 0u;
        if (oc < 18)
            v = pack2(pw[((size_t)oc*64 + c  )*9 + tap],
                      pw[((size_t)oc*64 + c+1)*9 + tap]);
        pwb[i] = v;
    }
}

// ---------------------------------------------------------------------------
// xprep: xt2[b][cg 8][y+8][col+8][cpl 8] u32 (interior). grid (128 y, 4 b).
// ---------------------------------------------------------------------------
__global__ __launch_bounds__(256) void k_xprep(
    const float* __restrict__ x, unsigned* __restrict__ xt)
{
    int y = blockIdx.x, b = blockIdx.y;
    int t = threadIdx.x;
    __shared__ float xsm[64*131];
    for (int ci0 = 0; ci0 < 128; ci0 += 64){
        for (int i=0;i<32;i++){
            int idx = t + 256*i;
            int col = idx & 127, ci = idx >> 7;
            xsm[ci*131 + col] = x[(((size_t)b*CIN + ci0+ci)*H + y)*W + col];
        }
        __syncthreads();
        for (int i=0;i<16;i++){
            int idx = t + 256*i;
            int cpg = idx & 31, col = idx >> 5;
            int cgg = (ci0 >> 4) + (cpg >> 3);
            int cpl = cpg & 7;
            unsigned u = pack2(xsm[(2*cpg)*131 + col], xsm[(2*cpg+1)*131 + col]);
            xt[((((size_t)b*8 + cgg)*XTD + y+8)*XTD + col+8)*8 + cpl] = u;
        }
        __syncthreads();
    }
}

// ---------------------------------------------------------------------------
// K1: dilated 3x3 conv via f16 MFMA implicit GEMM. grid 1024 1-D, XCD swizzle.
// (R4 structure: linear LDS + global_load_lds staging, conflict-free reads)
// ---------------------------------------------------------------------------
__global__ __launch_bounds__(256,3) void k_branch_mfma(
    const unsigned* __restrict__ xt, const unsigned* __restrict__ wbt,
    const float* __restrict__ b1, const float* __restrict__ b2,
    const float* __restrict__ b3, const float* __restrict__ b4,
    f16* __restrict__ feats2)
{
    int bid = blockIdx.x;
    int xcd = bid & 7;
    int j   = bid >> 3;
    int zb  = xcd + 8*(j & 1);
    int hp  = j >> 1;
    int d = zb >> 2, b = zb & 3;
    int dil = 2*d + 1;
    int h0 = hp*2;
    const float* bs = (d==0)?b1:(d==1)?b2:(d==2)?b3:b4;
    const float scale = (float)dil;

    __shared__ unsigned smem[6912 + 4608];     // As 27KB + Bs 18KB = 45KB
    unsigned* As = smem;
    unsigned* Bs = smem + 6912;
    const unsigned short* As16 = (const unsigned short*)As;
    const unsigned short* Bs16 = (const unsigned short*)Bs;

    int t = threadIdx.x;
    int lane = t & 63;
    int w = t >> 6;
    int l31 = lane & 31;
    int half = lane >> 5;

    f16* fb = feats2 + (size_t)zb*FSL;
    if (t < 32){
        int yy = h0 + 1 + (t>>4);
        int side = (t>>3)&1;
        int q = t & 7;
        uint4 z = make_uint4(0,0,0,0);
        *(uint4*)((unsigned short*)fb + ((size_t)yy*XW + side*129)*64 + q*8) = z;
    }
    if (hp == 0){
        uint4 z = make_uint4(0,0,0,0);
        for (int i=t; i<2080; i+=256){
            int row = i / 1040;
            int r = i % 1040;
            int xx = r >> 3, q = r & 7;
            *(uint4*)((unsigned short*)fb + ((size_t)(row*129)*XW + xx)*64 + q*8) = z;
        }
    }

    f32x16 acc[2][2];
    #pragma unroll
    for (int i=0;i<2;i++)
      #pragma unroll
      for (int jj=0;jj<2;jj++)
        #pragma unroll
        for (int e=0;e<16;e++) acc[i][jj][e] = 0.f;

    const unsigned* xtb_b = xt + (size_t)b*8*XTD*XTD*8;
    int r = w >> 1;
    int pxb = (w & 1) * 64;

    for (int cg=0; cg<8; cg++){
        const unsigned* xs_cg = xtb_b + (size_t)cg*XTD*XTD*8;
        #pragma unroll
        for (int i=0;i<7;i++){
            int idx4 = t + 256*i;
            if (idx4 < 1728){
                int row6 = idx4 / 288;
                int rem  = idx4 - row6*288;
                int hf   = rem / 144;
                int s    = rem - hf*144;
                int ky = row6 >> 1, rr = row6 & 1;
                int yy = h0 + rr + (ky-1)*dil + 8;
                gld16(xs_cg + ((size_t)yy*XTD + (s + 8 - dil))*8 + hf*4,
                      &As[idx4*4]);
            }
        }
        const unsigned* wb_cg = wbt + ((size_t)d*8 + cg)*4608;
        #pragma unroll
        for (int i=0;i<5;i++){
            int idx4 = t + 256*i;
            if (idx4 < 1152){
                int tap = idx4 >> 7;
                int hf  = (idx4 >> 6) & 1;
                int oc  = idx4 & 63;
                gld16(wb_cg + ((size_t)tap*64 + oc)*8 + hf*4,
                      &Bs[idx4*4]);
            }
        }
        __syncthreads();
        #pragma unroll
        for (int tap=0; tap<9; tap++){
            int ky = tap/3, kx = tap%3;
            int arow = ((ky*2 + r)*2 + half)*144;
            int brow = (tap*2 + half)*64;
            h16x8 a0  = *(const h16x8*)(As16 + (arow + pxb      + l31 + kx*dil)*8);
            h16x8 a1  = *(const h16x8*)(As16 + (arow + pxb + 32 + l31 + kx*dil)*8);
            h16x8 bb0 = *(const h16x8*)(Bs16 + (brow      + l31)*8);
            h16x8 bb1 = *(const h16x8*)(Bs16 + (brow + 32 + l31)*8);
            acc[0][0] = __builtin_amdgcn_mfma_f32_32x32x16_f16(a0, bb0, acc[0][0], 0,0,0);
            acc[0][1] = __builtin_amdgcn_mfma_f32_32x32x16_f16(a0, bb1, acc[0][1], 0,0,0);
            acc[1][0] = __builtin_amdgcn_mfma_f32_32x32x16_f16(a1, bb0, acc[1][0], 0,0,0);
            acc[1][1] = __builtin_amdgcn_mfma_f32_32x32x16_f16(a1, bb1, acc[1][1], 0,0,0);
        }
        __syncthreads();
    }

    unsigned short* ep = (unsigned short*)smem;   // 32KB overlay
    float bias0 = bs[l31], bias1 = bs[32 + l31];
    #pragma unroll
    for (int i=0;i<2;i++){
      #pragma unroll
      for (int jj=0;jj<2;jj++){
        int oc = jj*32 + l31;
        float bj = jj ? bias1 : bias0;
        #pragma unroll
        for (int rg=0; rg<4; rg++){
            int m0 = 64*w + 32*i + 8*rg + 4*half;
            #pragma unroll
            for (int e=0;e<4;e++)
                ep[(m0+e)*64 + oc] = b16u((acc[i][jj][4*rg+e] + bj)*scale);
        }
      }
    }
    __syncthreads();
    {
        int row = t >> 7, pxm = t & 127;
        unsigned short* drow = (unsigned short*)fb + ((size_t)(h0+1+row)*XW + pxm + 1)*64;
        const unsigned short* srow = ep + t*64;
        #pragma unroll
        for (int q=0;q<8;q++)
            *(uint4*)(drow + q*8) = *(const uint4*)(srow + q*8);
    }
}

// ---------------------------------------------------------------------------
// K2: 3x3 conv 64 -> 18 (offsets) via f16 MFMA, XCD swizzle.
// ---------------------------------------------------------------------------
__global__ __launch_bounds__(256,2) void k_offset_mfma(
    const f16* __restrict__ feats2,
    const unsigned* __restrict__ pwb,   // [tap][cq][hf][oc32][cl4] u32
    const float* __restrict__ pb,
    f16* __restrict__ offs)
{
    int bid = blockIdx.x;
    int xcd  = bid & 7;
    int h    = (bid >> 3) & 127;
    int pass = bid >> 10;
    int zb   = xcd + 8*pass;

    int t = threadIdx.x;
    int lane = t & 63, w = t >> 6;
    int l31 = lane & 31, half = lane >> 5;

    __shared__ unsigned short xs[3*132*68];   // 53.9 KB

    const unsigned short* fin = (const unsigned short*)(feats2 + (size_t)zb*FSL);
    for (int i=t; i<3120; i+=256){
        int row = i / 1040;
        int r   = i % 1040;
        int col = r >> 3, q = r & 7;
        uint4 v = *(const uint4*)(fin + ((size_t)(h+row)*XW + col)*64 + q*8);
        *(uint4*)&xs[(row*132 + col)*68 + q*8] = v;
    }
    __syncthreads();

    f32x16 acc;
    #pragma unroll
    for (int e=0;e<16;e++) acc[e] = 0.f;

    int pxw = 32*w + l31;
    #pragma unroll
    for (int tap=0; tap<9; tap++){
        int ky = tap/3, kx = tap%3;
        const unsigned short* arow = &xs[(ky*132 + pxw + kx)*68 + half*8];
        const unsigned* brow = pwb + (((size_t)tap*4)*2 + half)*128 + l31*4;
        #pragma unroll
        for (int cq=0; cq<4; cq++){
            h16x8 a  = *(const h16x8*)(arow + cq*16);
            h16x8 b0 = *(const h16x8*)(brow + cq*256);
            acc = __builtin_amdgcn_mfma_f32_32x32x16_f16(a, b0, acc, 0,0,0);
        }
    }
    __syncthreads();

    unsigned short* ep = (unsigned short*)xs;   // [oc 18][132 pad]
    if (l31 < 18){
        float bias = pb[l31];
        #pragma unroll
        for (int rg=0; rg<4; rg++){
            int m0 = 32*w + 4*half + 8*rg;
            #pragma unroll
            for (int e=0;e<4;e++)
                ep[l31*132 + m0+e] = b16u(acc[4*rg+e] + bias);
        }
    }
    __syncthreads();
    unsigned short* obase = (unsigned short*)(offs + (size_t)zb*18*HW) ;
    for (int i=t; i<288; i+=256){
        int oc = i >> 4, sg = i & 15;
        *(uint4*)(obase + (size_t)oc*HW + h*W + sg*8) = *(const uint4*)(ep + oc*132 + sg*8);
    }
}

// ---------------------------------------------------------------------------
// K3a: deform sampling + dw einsum via f16 MFMA — R3 proven structure
// (staged B in LDS, single coords buffer, 3 barriers/tap) at 5 blocks/CU
// (LDS 30.2KB x 5 = 151KB fits; was capped at 4 by launch_bounds).
// grid 2048 1-D, XCD swizzle.
// ---------------------------------------------------------------------------
__global__ __launch_bounds__(256,5) void k_deform_mfma(
    const f16* __restrict__ feats2,
    const f16* __restrict__ offs,
    const unsigned* __restrict__ dwb2,  // [n][oc][cp32] u32
    const float* __restrict__ db,
    f16* __restrict__ dout2)
{
    int bid = blockIdx.x;
    int xcd  = bid & 7;
    int h    = (bid >> 3) & 127;
    int pass = bid >> 10;
    int zb   = xcd + 8*pass;

    int t = threadIdx.x;
    int lane = t & 63, w = t >> 6;
    int l31 = lane & 31, half = lane >> 5;
    int pxg = t >> 3;                 // 0..31, pixel group (gather phase)
    int cq  = t & 7;                  // which 8-ch slice of the 64-ch line
    int sub_w = cq >> 1;              // A-frag sub (0..3)
    int hf8   = cq & 1;               // A-frag half (0..1)

    #define AROW 516                   // u32 row stride (8 rows)
    __shared__ unsigned smem_d[8*AROW + 2304 + 1024];  // A 16.5KB + B 9.2KB + coords 4KB
    unsigned* Asu = smem_d;
    unsigned* Bsu = smem_d + 8*AROW;
    unsigned* Cd  = smem_d + 8*AROW + 2304;   // [px 128][8]

    const f16* obase = offs + (size_t)zb*18*HW + h*W;
    const unsigned short* fbase = (const unsigned short*)(feats2 + (size_t)zb*FSL);

    f32x16 acc0, acc1;
    #pragma unroll
    for (int e=0;e<16;e++){ acc0[e]=0.f; acc1[e]=0.f; }

#define CLOAD(S, C0, C1) { \
    const unsigned* cp_ = Cd + ((S)*32 + pxg)*8; \
    C0 = *(const uint4*)cp_; \
    C1 = *(const uint4*)(cp_ + 4); }
#define GLOAD(C1, LT, LB, RT, RB) { \
    int dxo_ = (int)(C1).y, dyo_ = (int)(C1).z; \
    const unsigned short* fc_ = fbase + (int)(C1).x + cq*8; \
    LT = *(const uint4*)(fc_); \
    LB = *(const uint4*)(fc_ + dxo_); \
    RT = *(const uint4*)(fc_ + dyo_); \
    RB = *(const uint4*)(fc_ + dyo_ + dxo_); }
#define INTERP(S, C0, LT, LB, RT, RB) { \
    __half2 wlt_ = uh2((C0).x), wlb_ = uh2((C0).y); \
    __half2 wrt_ = uh2((C0).z), wrb_ = uh2((C0).w); \
    unsigned p0_,p1_,p2_,p3_; \
    { __half2 r_ = __hmul2(wlt_, uh2((LT).x)); r_ = __hfma2(wlb_, uh2((LB).x), r_); \
      r_ = __hfma2(wrt_, uh2((RT).x), r_); r_ = __hfma2(wrb_, uh2((RB).x), r_); p0_ = h2u(r_); } \
    { __half2 r_ = __hmul2(wlt_, uh2((LT).y)); r_ = __hfma2(wlb_, uh2((LB).y), r_); \
      r_ = __hfma2(wrt_, uh2((RT).y), r_); r_ = __hfma2(wrb_, uh2((RB).y), r_); p1_ = h2u(r_); } \
    { __half2 r_ = __hmul2(wlt_, uh2((LT).z)); r_ = __hfma2(wlb_, uh2((LB).z), r_); \
      r_ = __hfma2(wrt_, uh2((RT).z), r_); r_ = __hfma2(wrb_, uh2((RB).z), r_); p2_ = h2u(r_); } \
    { __half2 r_ = __hmul2(wlt_, uh2((LT).w)); r_ = __hfma2(wlb_, uh2((LB).w), r_); \
      r_ = __hfma2(wrt_, uh2((RT).w), r_); r_ = __hfma2(wrb_, uh2((RB).w), r_); p3_ = h2u(r_); } \
    uint4 av_; av_.x=p0_; av_.y=p1_; av_.z=p2_; av_.w=p3_; \
    *(uint4*)&Asu[(sub_w*2 + hf8)*AROW + ((S)*32 + pxg)*4] = av_; }

    for (int n=0; n<9; n++){
        // stage B for this n
        const uint4* dsrc = (const uint4*)(dwb2 + n*2048);
        #pragma unroll
        for (int i=0;i<2;i++){
            int j = t + 256*i;
            int idx4 = j*4;
            int oc = idx4 >> 5, cp = idx4 & 31;
            *(uint4*)&Bsu[oc*36 + cp] = dsrc[j];
        }
        // cooperative coords: thread t<128 computes pixel t once
        if (t < 128){
            float offy = b2f(obase[n*HW + t]);
            float offx = b2f(obase[(n+9)*HW + t]);
            float py  = (float)(h + n/3) + offy;
            float pxf = (float)(t + n%3) + offx;
            float fy = floorf(py), fx = floorf(pxf);
            float lty = fminf(fmaxf(fy,     0.f),129.f);
            float ltx = fminf(fmaxf(fx,     0.f),129.f);
            float rby = fminf(fmaxf(fy+1.f, 0.f),129.f);
            float rbx = fminf(fmaxf(fx+1.f, 0.f),129.f);
            float pyc = fminf(fmaxf(py,     0.f),129.f);
            float pxc = fminf(fmaxf(pxf,    0.f),129.f);
            float ay = 1.f + (lty-pyc), by = 1.f - (rby-pyc);
            float ax = 1.f + (ltx-pxc), bx = 1.f - (rbx-pxc);
            unsigned* cp = &Cd[t*8];
            cp[0] = bcasth2(ay*ax);
            cp[1] = bcasth2(ay*bx);
            cp[2] = bcasth2(by*ax);
            cp[3] = bcasth2(by*bx);
            cp[4] = (unsigned)(((int)lty*XW + (int)ltx)*64);
            cp[5] = (unsigned)(((int)rbx - (int)ltx)*64);
            cp[6] = (unsigned)(((int)rby - (int)lty)*XW*64);
        }
        __syncthreads();

        // 2-deep pipelined gather: named register sets a/b, constant indices
        {
            uint4 c0a, c1a, c0b, c1b;
            uint4 LTa, LBa, RTa, RBa;
            uint4 LTb, LBb, RTb, RBb;
            CLOAD(0, c0a, c1a); GLOAD(c1a, LTa, LBa, RTa, RBa);
            CLOAD(1, c0b, c1b); GLOAD(c1b, LTb, LBb, RTb, RBb);
            INTERP(0, c0a, LTa, LBa, RTa, RBa);
            CLOAD(2, c0a, c1a); GLOAD(c1a, LTa, LBa, RTa, RBa);
            INTERP(1, c0b, LTb, LBb, RTb, RBb);
            CLOAD(3, c0b, c1b); GLOAD(c1b, LTb, LBb, RTb, RBb);
            INTERP(2, c0a, LTa, LBa, RTa, RBa);
            INTERP(3, c0b, LTb, LBb, RTb, RBb);
        }
        __syncthreads();

        const unsigned short* As16 = (const unsigned short*)Asu;
        const unsigned short* Bs16 = (const unsigned short*)Bsu;
        #pragma unroll
        for (int s=0;s<4;s++){
            h16x8 a  = *(const h16x8*)(As16 + (s*2+half)*(AROW*2) + (32*w + l31)*8);
            h16x8 b0 = *(const h16x8*)(Bs16 + (l31*36 + s*8 + half*4)*2);
            h16x8 b1 = *(const h16x8*)(Bs16 + ((32+l31)*36 + s*8 + half*4)*2);
            acc0 = __builtin_amdgcn_mfma_f32_32x32x16_f16(a, b0, acc0, 0,0,0);
            acc1 = __builtin_amdgcn_mfma_f32_32x32x16_f16(a, b1, acc1, 0,0,0);
        }
        __syncthreads();
    }
#undef CLOAD
#undef GLOAD
#undef INTERP

    // epilogue: +db, ep[px][oc] u16 == dout2 row layout, straight copy out
    unsigned short* ep = (unsigned short*)smem_d;   // overlay (safe: barrier above)
    #pragma unroll
    for (int nt=0; nt<2; nt++){
        int oc = nt*32 + l31;
        float bias = db[oc];
        const f32x16& A = nt ? acc1 : acc0;
        #pragma unroll
        for (int rg=0; rg<4; rg++){
            int m0 = 32*w + 4*half + 8*rg;
            #pragma unroll
            for (int e=0;e<4;e++)
                ep[(m0+e)*64 + oc] = b16u(A[4*rg+e] + bias);
        }
    }
    __syncthreads();
    uint4* dst = (uint4*)((unsigned short*)dout2 + ((size_t)zb*128 + h)*(128*64));
    #pragma unroll
    for (int i=0;i<4;i++)
        dst[t + 256*i] = ((const uint4*)ep)[t + 256*i];
    #undef AROW
}

// ---------------------------------------------------------------------------
// K3b: 1x1 conv 256 -> 64 + cb + ReLU via f16 MFMA. grid (128 h, 4 b).
// A direct from dout2 (16-deep prefetch), B direct from L1-hot cwb2
// [kc][hf][oc][cl4]. Zero main-loop barriers.
// ---------------------------------------------------------------------------
__global__ __launch_bounds__(256,2) void k_combine_mfma(
    const f16* __restrict__ dout2,
    const unsigned* __restrict__ cwb2,  // [kc][hf][oc][cl4] u32
    const float* __restrict__ cb,
    float* __restrict__ out)
{
    int h = blockIdx.x, b = blockIdx.y;
    int t = threadIdx.x;
    int lane = t & 63, w = t >> 6, l31 = lane & 31, half = lane >> 5;

    __shared__ float ep2[64*132];   // 33.8 KB epilogue transpose

    f32x16 acc0, acc1;
    #pragma unroll
    for (int e=0;e<16;e++){ acc0[e]=0.f; acc1[e]=0.f; }

    const unsigned short* dbase0 = (const unsigned short*)dout2;
    const unsigned short* cb16 = (const unsigned short*)cwb2;
    size_t rowsel2 = ((size_t)b*128 + h)*128 + (32*w + l31);

    // issue all 16 A-fragment loads (16B each) up-front
    unsigned AV[64];
    #pragma unroll
    for (int kc=0; kc<16; kc++){
        *(uint4*)&AV[kc*4] = *(const uint4*)(
            dbase0 + (size_t)(kc>>2)*(4*HW*64) + rowsel2*64 + (kc&3)*16 + half*8);
    }
    #pragma unroll
    for (int kc=0; kc<16; kc++){
        h16x8 a  = __builtin_bit_cast(h16x8, *(uint4*)&AV[kc*4]);
        h16x8 b0 = *(const h16x8*)(cb16 + ((kc*2+half)*64 + l31)*8);
        h16x8 b1 = *(const h16x8*)(cb16 + ((kc*2+half)*64 + 32+l31)*8);
        acc0 = __builtin_amdgcn_mfma_f32_32x32x16_f16(a, b0, acc0, 0,0,0);
        acc1 = __builtin_amdgcn_mfma_f32_32x32x16_f16(a, b1, acc1, 0,0,0);
    }

    #pragma unroll
    for (int nt=0; nt<2; nt++){
        int oc = nt*32 + l31;
        float bias = cb[oc];
        const f32x16& A = nt ? acc1 : acc0;
        #pragma unroll
        for (int rg=0; rg<4; rg++){
            int m0 = 32*w + 4*half + 8*rg;
            #pragma unroll
            for (int e=0;e<4;e++)
                ep2[oc*132 + m0+e] = fmaxf(A[4*rg+e] + bias, 0.f);
        }
    }
    __syncthreads();
    for (int i=t; i<2048; i+=256){
        int oc = i>>5, sg = i&31;
        *(uint4*)&out[(((size_t)b*64+oc)*128 + h)*128 + sg*4] = *(const uint4*)&ep2[oc*132 + sg*4];
    }
}

extern "C" void kernel_launch(void* const* d_in, const int* in_sizes, int n_in,
                              void* d_out, int out_size, void* d_ws, size_t ws_size,
                              hipStream_t stream) {
    const float* x  = (const float*)d_in[0];
    const float* w1 = (const float*)d_in[1];
    const float* b1 = (const float*)d_in[2];
    const float* w2 = (const float*)d_in[3];
    const float* b2 = (const float*)d_in[4];
    const float* w3 = (const float*)d_in[5];
    const float* b3 = (const float*)d_in[6];
    const float* w4 = (const float*)d_in[7];
    const float* b4 = (const float*)d_in[8];
    const float* pw = (const float*)d_in[9];
    const float* pb = (const float*)d_in[10];
    const float* dw = (const float*)d_in[11];
    const float* db = (const float*)d_in[12];
    const float* cw = (const float*)d_in[13];
    const float* cb = (const float*)d_in[14];
    float* out = (float*)d_out;

    f16* feats2 = (f16*)d_ws;                               // 34.6 MB
    f16* offs   = feats2 + (size_t)16*FSL;                  // 9.4 MB
    f16* region2 = offs + (size_t)16*18*HW;
    f16* dout2  = region2;                                  // 33.55 MB
    unsigned* xt  = (unsigned*)region2;                     // 21.2 MB (dead before dout2)
    unsigned* wbt = xt + (size_t)4*8*XTD*XTD*8;             // 0.59 MB (dead before dout2)
    unsigned* dwb2 = (unsigned*)(dout2 + (size_t)16*128*128*64);  // 73.7 KB
    unsigned* cwb2 = dwb2 + 18432;                          // 32.8 KB
    unsigned* pwb  = cwb2 + 8192;                           // 36.9 KB

    k_prep        <<<dim3(1740),    256, 0, stream>>>(w1,w2,w3,w4, dw, cw, pw,
                                                      (uint4*)xt, wbt, dwb2, cwb2, pwb);
    k_xprep       <<<dim3(128,4),   256, 0, stream>>>(x, xt);
    k_branch_mfma <<<dim3(1024),    256, 0, stream>>>(xt, wbt, b1,b2,b3,b4, feats2);
    k_offset_mfma <<<dim3(2048),    256, 0, stream>>>(feats2, pwb, pb, offs);
    k_deform_mfma <<<dim3(2048),    256, 0, stream>>>(feats2, offs, dwb2, db, dout2);
    k_combine_mfma<<<dim3(128,4),   256, 0, stream>>>(dout2, cwb2, cb, out);
}

// Round 9
// 269.109 us; speedup vs baseline: 1.1502x; 1.0755x over previous
//
#include <hip/hip_runtime.h>
#include <hip/hip_fp16.h>

#define H 128
#define W 128
#define CIN 128
#define COUT 64
#define HW (H*W)
#define XW 130                    // padded spatial dim (y,x in [0,129])
#define FSL (XW*XW*64)            // feats2 elems per zb slice (NHWC f16)
#define XTD 144                   // xt padded dim

typedef __half f16;
typedef __attribute__((ext_vector_type(8)))  _Float16 h16x8;
typedef __attribute__((ext_vector_type(16))) float f32x16;

__device__ __forceinline__ float b2f(f16 v){ return __half2float(v); }
__device__ __forceinline__ f16  f2b(float v){ return __float2half_rn(v); }
__device__ __forceinline__ unsigned pack2(float a, float b){
    unsigned short ua = __builtin_bit_cast(unsigned short, f2b(a));
    unsigned short ub = __builtin_bit_cast(unsigned short, f2b(b));
    return (unsigned)ua | ((unsigned)ub << 16);
}
__device__ __forceinline__ unsigned short b16u(float v){
    return __builtin_bit_cast(unsigned short, f2b(v));
}
__device__ __forceinline__ __half2 uh2(unsigned u){
    return __builtin_bit_cast(__half2, u);
}
__device__ __forceinline__ unsigned h2u(__half2 v){
    return __builtin_bit_cast(unsigned, v);
}
__device__ __forceinline__ unsigned bcasth2(float v){
    __half h = __float2half_rn(v);
    return h2u(__halves2half2(h, h));
}
// async global->LDS, 16B per lane; lds dest must be linear in lane id
__device__ __forceinline__ void gld16(const void* g, void* l){
    __builtin_amdgcn_global_load_lds(
        (const __attribute__((address_space(1))) void*)g,
        (__attribute__((address_space(3))) void*)l, 16, 0, 0);
}

// ---------------------------------------------------------------------------
// k_prep: [0,1024) zero xt2; [1024,1600) wbt; [1600,1672) dwb2;
//         [1672,1704) cwb2; [1704,1740) pwb      (all tables packed f16 pairs)
// dwb2 [n][oc][cp32] (R3 staged-B layout); cwb2 [kc][hf][oc][cl4] (direct-B).
// ---------------------------------------------------------------------------
__global__ __launch_bounds__(256) void k_prep(
    const float* __restrict__ w1, const float* __restrict__ w2,
    const float* __restrict__ w3, const float* __restrict__ w4,
    const float* __restrict__ dw, const float* __restrict__ cw,
    const float* __restrict__ pw,
    uint4* __restrict__ xt4, unsigned* __restrict__ wbt,
    unsigned* __restrict__ dwb2, unsigned* __restrict__ cwb2,
    unsigned* __restrict__ pwb)
{
    int bid = blockIdx.x;
    int t = threadIdx.x;
    if (bid < 1024){
        const int n4 = (4*XTD*XTD*64)/4;        // 1327104
        for (int i = bid*256 + t; i < n4; i += 1024*256)
            xt4[i] = make_uint4(0,0,0,0);
    } else if (bid < 1600){
        int tid = (bid-1024)*256 + t;            // 147456 = 4*8*9*64*8
        int cpl = tid & 7;
        int oc  = (tid >> 3) & 63;
        int tap = (tid >> 9) % 9;
        int cg  = (tid / 4608) & 7;
        int d   = tid / 36864;
        const float* wt = (d==0)?w1:(d==1)?w2:(d==2)?w3:w4;
        int c = cg*8 + cpl;
        wbt[tid] = pack2(wt[((size_t)oc*CIN + 2*c  )*9 + tap],
                         wt[((size_t)oc*CIN + 2*c+1)*9 + tap]);
    } else if (bid < 1672){
        int i = (bid-1600)*256 + t;              // 18432: dwb2[n][oc][cp32]
        int n = i>>11, oc = (i>>5)&63, cp = i&31;
        dwb2[i] = pack2(dw[((size_t)oc*64 + 2*cp  )*9 + n],
                        dw[((size_t)oc*64 + 2*cp+1)*9 + n]);
    } else if (bid < 1704){
        int i = (bid-1672)*256 + t;              // 8192: cwb2[kc][hf][oc][cl4]
        int kc = i>>9;
        int hf = (i>>8)&1;
        int oc = (i>>2)&63;
        int cl = i&3;
        int cp = kc*8 + hf*4 + cl;               // channel-pair 0..127
        cwb2[i] = pack2(cw[(size_t)oc*256 + 2*cp], cw[(size_t)oc*256 + 2*cp+1]);
    } else {
        int i = (bid-1704)*256 + t;              // 9216
        int cl = i & 3, oc = (i>>2)&31, hf = (i>>7)&1, cq = (i>>8)&3, tap = i>>10;
        int c = cq*16 + hf*8 + cl*2;
        unsigned v = 0u;
        if (oc < 18)
            v = pack2(pw[((size_t)oc*64 + c  )*9 + tap],
                      pw[((size_t)oc*64 + c+1)*9 + tap]);
        pwb[i] = v;
    }
}

// ---------------------------------------------------------------------------
// xprep: xt2[b][cg 8][y+8][col+8][cpl 8] u32 (interior). grid (128 y, 4 b).
// ---------------------------------------------------------------------------
__global__ __launch_bounds__(256) void k_xprep(
    const float* __restrict__ x, unsigned* __restrict__ xt)
{
    int y = blockIdx.x, b = blockIdx.y;
    int t = threadIdx.x;
    __shared__ float xsm[64*131];
    for (int ci0 = 0; ci0 < 128; ci0 += 64){
        for (int i=0;i<32;i++){
            int idx = t + 256*i;
            int col = idx & 127, ci = idx >> 7;
            xsm[ci*131 + col] = x[(((size_t)b*CIN + ci0+ci)*H + y)*W + col];
        }
        __syncthreads();
        for (int i=0;i<16;i++){
            int idx = t + 256*i;
            int cpg = idx & 31, col = idx >> 5;
            int cgg = (ci0 >> 4) + (cpg >> 3);
            int cpl = cpg & 7;
            unsigned u = pack2(xsm[(2*cpg)*131 + col], xsm[(2*cpg+1)*131 + col]);
            xt[((((size_t)b*8 + cgg)*XTD + y+8)*XTD + col+8)*8 + cpl] = u;
        }
        __syncthreads();
    }
}

// ---------------------------------------------------------------------------
// K1: dilated 3x3 conv via f16 MFMA implicit GEMM. grid 1024 1-D, XCD swizzle.
// (R4 structure: linear LDS + global_load_lds staging, conflict-free reads)
// ---------------------------------------------------------------------------
__global__ __launch_bounds__(256,3) void k_branch_mfma(
    const unsigned* __restrict__ xt, const unsigned* __restrict__ wbt,
    const float* __restrict__ b1, const float* __restrict__ b2,
    const float* __restrict__ b3, const float* __restrict__ b4,
    f16* __restrict__ feats2)
{
    int bid = blockIdx.x;
    int xcd = bid & 7;
    int j   = bid >> 3;
    int zb  = xcd + 8*(j & 1);
    int hp  = j >> 1;
    int d = zb >> 2, b = zb & 3;
    int dil = 2*d + 1;
    int h0 = hp*2;
    const float* bs = (d==0)?b1:(d==1)?b2:(d==2)?b3:b4;
    const float scale = (float)dil;

    __shared__ unsigned smem[6912 + 4608];     // As 27KB + Bs 18KB = 45KB
    unsigned* As = smem;
    unsigned* Bs = smem + 6912;
    const unsigned short* As16 = (const unsigned short*)As;
    const unsigned short* Bs16 = (const unsigned short*)Bs;

    int t = threadIdx.x;
    int lane = t & 63;
    int w = t >> 6;
    int l31 = lane & 31;
    int half = lane >> 5;

    f16* fb = feats2 + (size_t)zb*FSL;
    if (t < 32){
        int yy = h0 + 1 + (t>>4);
        int side = (t>>3)&1;
        int q = t & 7;
        uint4 z = make_uint4(0,0,0,0);
        *(uint4*)((unsigned short*)fb + ((size_t)yy*XW + side*129)*64 + q*8) = z;
    }
    if (hp == 0){
        uint4 z = make_uint4(0,0,0,0);
        for (int i=t; i<2080; i+=256){
            int row = i / 1040;
            int r = i % 1040;
            int xx = r >> 3, q = r & 7;
            *(uint4*)((unsigned short*)fb + ((size_t)(row*129)*XW + xx)*64 + q*8) = z;
        }
    }

    f32x16 acc[2][2];
    #pragma unroll
    for (int i=0;i<2;i++)
      #pragma unroll
      for (int jj=0;jj<2;jj++)
        #pragma unroll
        for (int e=0;e<16;e++) acc[i][jj][e] = 0.f;

    const unsigned* xtb_b = xt + (size_t)b*8*XTD*XTD*8;
    int r = w >> 1;
    int pxb = (w & 1) * 64;

    for (int cg=0; cg<8; cg++){
        const unsigned* xs_cg = xtb_b + (size_t)cg*XTD*XTD*8;
        #pragma unroll
        for (int i=0;i<7;i++){
            int idx4 = t + 256*i;
            if (idx4 < 1728){
                int row6 = idx4 / 288;
                int rem  = idx4 - row6*288;
                int hf   = rem / 144;
                int s    = rem - hf*144;
                int ky = row6 >> 1, rr = row6 & 1;
                int yy = h0 + rr + (ky-1)*dil + 8;
                gld16(xs_cg + ((size_t)yy*XTD + (s + 8 - dil))*8 + hf*4,
                      &As[idx4*4]);
            }
        }
        const unsigned* wb_cg = wbt + ((size_t)d*8 + cg)*4608;
        #pragma unroll
        for (int i=0;i<5;i++){
            int idx4 = t + 256*i;
            if (idx4 < 1152){
                int tap = idx4 >> 7;
                int hf  = (idx4 >> 6) & 1;
                int oc  = idx4 & 63;
                gld16(wb_cg + ((size_t)tap*64 + oc)*8 + hf*4,
                      &Bs[idx4*4]);
            }
        }
        __syncthreads();
        #pragma unroll
        for (int tap=0; tap<9; tap++){
            int ky = tap/3, kx = tap%3;
            int arow = ((ky*2 + r)*2 + half)*144;
            int brow = (tap*2 + half)*64;
            h16x8 a0  = *(const h16x8*)(As16 + (arow + pxb      + l31 + kx*dil)*8);
            h16x8 a1  = *(const h16x8*)(As16 + (arow + pxb + 32 + l31 + kx*dil)*8);
            h16x8 bb0 = *(const h16x8*)(Bs16 + (brow      + l31)*8);
            h16x8 bb1 = *(const h16x8*)(Bs16 + (brow + 32 + l31)*8);
            acc[0][0] = __builtin_amdgcn_mfma_f32_32x32x16_f16(a0, bb0, acc[0][0], 0,0,0);
            acc[0][1] = __builtin_amdgcn_mfma_f32_32x32x16_f16(a0, bb1, acc[0][1], 0,0,0);
            acc[1][0] = __builtin_amdgcn_mfma_f32_32x32x16_f16(a1, bb0, acc[1][0], 0,0,0);
            acc[1][1] = __builtin_amdgcn_mfma_f32_32x32x16_f16(a1, bb1, acc[1][1], 0,0,0);
        }
        __syncthreads();
    }

    unsigned short* ep = (unsigned short*)smem;   // 32KB overlay
    float bias0 = bs[l31], bias1 = bs[32 + l31];
    #pragma unroll
    for (int i=0;i<2;i++){
      #pragma unroll
      for (int jj=0;jj<2;jj++){
        int oc = jj*32 + l31;
        float bj = jj ? bias1 : bias0;
        #pragma unroll
        for (int rg=0; rg<4; rg++){
            int m0 = 64*w + 32*i + 8*rg + 4*half;
            #pragma unroll
            for (int e=0;e<4;e++)
                ep[(m0+e)*64 + oc] = b16u((acc[i][jj][4*rg+e] + bj)*scale);
        }
      }
    }
    __syncthreads();
    {
        int row = t >> 7, pxm = t & 127;
        unsigned short* drow = (unsigned short*)fb + ((size_t)(h0+1+row)*XW + pxm + 1)*64;
        const unsigned short* srow = ep + t*64;
        #pragma unroll
        for (int q=0;q<8;q++)
            *(uint4*)(drow + q*8) = *(const uint4*)(srow + q*8);
    }
}

// ---------------------------------------------------------------------------
// K2: 3x3 conv 64 -> 18 (offsets) via f16 MFMA, XCD swizzle.
// R9: linear [row][col][qphys] LDS (no pad) -> gld16 async staging with
// XOR pre-swizzled global source (qsrc = q ^ (col&7)); MFMA reads apply the
// same XOR (residual 4-way conflict vs 32-way unswizzled). LDS 48.8KB,
// 3 blocks/CU.
// ---------------------------------------------------------------------------
__global__ __launch_bounds__(256,3) void k_offset_mfma(
    const f16* __restrict__ feats2,
    const unsigned* __restrict__ pwb,   // [tap][cq][hf][oc32][cl4] u32
    const float* __restrict__ pb,
    f16* __restrict__ offs)
{
    int bid = blockIdx.x;
    int xcd  = bid & 7;
    int h    = (bid >> 3) & 127;
    int pass = bid >> 10;
    int zb   = xcd + 8*pass;

    int t = threadIdx.x;
    int lane = t & 63, w = t >> 6;
    int l31 = lane & 31, half = lane >> 5;

    __shared__ unsigned short xs[3120*8];   // [row 3][col 130][qphys 8] granules, 48.75 KB

    const unsigned short* fin = (const unsigned short*)(feats2 + (size_t)zb*FSL);
    #pragma unroll
    for (int i=0; i<13; i++){
        int idx4 = t + 256*i;
        if (idx4 < 3120){
            int row = idx4 / 1040;
            int r   = idx4 - row*1040;
            int col = r >> 3, q = r & 7;
            int qsrc = q ^ (col & 7);
            gld16(fin + ((size_t)(h+row)*XW + col)*64 + qsrc*8,
                  &xs[idx4*8]);
        }
    }
    __syncthreads();

    f32x16 acc;
    #pragma unroll
    for (int e=0;e<16;e++) acc[e] = 0.f;

    int pxw = 32*w + l31;
    #pragma unroll
    for (int tap=0; tap<9; tap++){
        int ky = tap/3, kx = tap%3;
        int col = pxw + kx;
        int gbase = (ky*130 + col)*8;
        int csw = col & 7;
        const unsigned* brow = pwb + (((size_t)tap*4)*2 + half)*128 + l31*4;
        #pragma unroll
        for (int cq=0; cq<4; cq++){
            int q = cq*2 + half;
            h16x8 a  = *(const h16x8*)&xs[(gbase + (q ^ csw))*8];
            h16x8 b0 = *(const h16x8*)(brow + cq*256);
            acc = __builtin_amdgcn_mfma_f32_32x32x16_f16(a, b0, acc, 0,0,0);
        }
    }
    __syncthreads();

    unsigned short* ep = (unsigned short*)xs;   // [oc 18][132 pad] overlay
    if (l31 < 18){
        float bias = pb[l31];
        #pragma unroll
        for (int rg=0; rg<4; rg++){
            int m0 = 32*w + 4*half + 8*rg;
            #pragma unroll
            for (int e=0;e<4;e++)
                ep[l31*132 + m0+e] = b16u(acc[4*rg+e] + bias);
        }
    }
    __syncthreads();
    unsigned short* obase = (unsigned short*)(offs + (size_t)zb*18*HW) ;
    for (int i=t; i<288; i+=256){
        int oc = i >> 4, sg = i & 15;
        *(uint4*)(obase + (size_t)oc*HW + h*W + sg*8) = *(const uint4*)(ep + oc*132 + sg*8);
    }
}

// ---------------------------------------------------------------------------
// K3a: deform sampling + dw einsum via f16 MFMA — R3 proven structure
// (staged B in LDS, single coords buffer, 3 barriers/tap).
// grid 2048 1-D, XCD swizzle.
// ---------------------------------------------------------------------------
__global__ __launch_bounds__(256,5) void k_deform_mfma(
    const f16* __restrict__ feats2,
    const f16* __restrict__ offs,
    const unsigned* __restrict__ dwb2,  // [n][oc][cp32] u32
    const float* __restrict__ db,
    f16* __restrict__ dout2)
{
    int bid = blockIdx.x;
    int xcd  = bid & 7;
    int h    = (bid >> 3) & 127;
    int pass = bid >> 10;
    int zb   = xcd + 8*pass;

    int t = threadIdx.x;
    int lane = t & 63, w = t >> 6;
    int l31 = lane & 31, half = lane >> 5;
    int pxg = t >> 3;                 // 0..31, pixel group (gather phase)
    int cq  = t & 7;                  // which 8-ch slice of the 64-ch line
    int sub_w = cq >> 1;              // A-frag sub (0..3)
    int hf8   = cq & 1;               // A-frag half (0..1)

    #define AROW 516                   // u32 row stride (8 rows)
    __shared__ unsigned smem_d[8*AROW + 2304 + 1024];  // A 16.5KB + B 9.2KB + coords 4KB
    unsigned* Asu = smem_d;
    unsigned* Bsu = smem_d + 8*AROW;
    unsigned* Cd  = smem_d + 8*AROW + 2304;   // [px 128][8]

    const f16* obase = offs + (size_t)zb*18*HW + h*W;
    const unsigned short* fbase = (const unsigned short*)(feats2 + (size_t)zb*FSL);

    f32x16 acc0, acc1;
    #pragma unroll
    for (int e=0;e<16;e++){ acc0[e]=0.f; acc1[e]=0.f; }

#define CLOAD(S, C0, C1) { \
    const unsigned* cp_ = Cd + ((S)*32 + pxg)*8; \
    C0 = *(const uint4*)cp_; \
    C1 = *(const uint4*)(cp_ + 4); }
#define GLOAD(C1, LT, LB, RT, RB) { \
    int dxo_ = (int)(C1).y, dyo_ = (int)(C1).z; \
    const unsigned short* fc_ = fbase + (int)(C1).x + cq*8; \
    LT = *(const uint4*)(fc_); \
    LB = *(const uint4*)(fc_ + dxo_); \
    RT = *(const uint4*)(fc_ + dyo_); \
    RB = *(const uint4*)(fc_ + dyo_ + dxo_); }
#define INTERP(S, C0, LT, LB, RT, RB) { \
    __half2 wlt_ = uh2((C0).x), wlb_ = uh2((C0).y); \
    __half2 wrt_ = uh2((C0).z), wrb_ = uh2((C0).w); \
    unsigned p0_,p1_,p2_,p3_; \
    { __half2 r_ = __hmul2(wlt_, uh2((LT).x)); r_ = __hfma2(wlb_, uh2((LB).x), r_); \
      r_ = __hfma2(wrt_, uh2((RT).x), r_); r_ = __hfma2(wrb_, uh2((RB).x), r_); p0_ = h2u(r_); } \
    { __half2 r_ = __hmul2(wlt_, uh2((LT).y)); r_ = __hfma2(wlb_, uh2((LB).y), r_); \
      r_ = __hfma2(wrt_, uh2((RT).y), r_); r_ = __hfma2(wrb_, uh2((RB).y), r_); p1_ = h2u(r_); } \
    { __half2 r_ = __hmul2(wlt_, uh2((LT).z)); r_ = __hfma2(wlb_, uh2((LB).z), r_); \
      r_ = __hfma2(wrt_, uh2((RT).z), r_); r_ = __hfma2(wrb_, uh2((RB).z), r_); p2_ = h2u(r_); } \
    { __half2 r_ = __hmul2(wlt_, uh2((LT).w)); r_ = __hfma2(wlb_, uh2((LB).w), r_); \
      r_ = __hfma2(wrt_, uh2((RT).w), r_); r_ = __hfma2(wrb_, uh2((RB).w), r_); p3_ = h2u(r_); } \
    uint4 av_; av_.x=p0_; av_.y=p1_; av_.z=p2_; av_.w=p3_; \
    *(uint4*)&Asu[(sub_w*2 + hf8)*AROW + ((S)*32 + pxg)*4] = av_; }

    for (int n=0; n<9; n++){
        // stage B for this n
        const uint4* dsrc = (const uint4*)(dwb2 + n*2048);
        #pragma unroll
        for (int i=0;i<2;i++){
            int j = t + 256*i;
            int idx4 = j*4;
            int oc = idx4 >> 5, cp = idx4 & 31;
            *(uint4*)&Bsu[oc*36 + cp] = dsrc[j];
        }
        // cooperative coords: thread t<128 computes pixel t once
        if (t < 128){
            float offy = b2f(obase[n*HW + t]);
            float offx = b2f(obase[(n+9)*HW + t]);
            float py  = (float)(h + n/3) + offy;
            float pxf = (float)(t + n%3) + offx;
            float fy = floorf(py), fx = floorf(pxf);
            float lty = fminf(fmaxf(fy,     0.f),129.f);
            float ltx = fminf(fmaxf(fx,     0.f),129.f);
            float rby = fminf(fmaxf(fy+1.f, 0.f),129.f);
            float rbx = fminf(fmaxf(fx+1.f, 0.f),129.f);
            float pyc = fminf(fmaxf(py,     0.f),129.f);
            float pxc = fminf(fmaxf(pxf,    0.f),129.f);
            float ay = 1.f + (lty-pyc), by = 1.f - (rby-pyc);
            float ax = 1.f + (ltx-pxc), bx = 1.f - (rbx-pxc);
            unsigned* cp = &Cd[t*8];
            cp[0] = bcasth2(ay*ax);
            cp[1] = bcasth2(ay*bx);
            cp[2] = bcasth2(by*ax);
            cp[3] = bcasth2(by*bx);
            cp[4] = (unsigned)(((int)lty*XW + (int)ltx)*64);
            cp[5] = (unsigned)(((int)rbx - (int)ltx)*64);
            cp[6] = (unsigned)(((int)rby - (int)lty)*XW*64);
        }
        __syncthreads();

        // 2-deep pipelined gather: named register sets a/b, constant indices
        {
            uint4 c0a, c1a, c0b, c1b;
            uint4 LTa, LBa, RTa, RBa;
            uint4 LTb, LBb, RTb, RBb;
            CLOAD(0, c0a, c1a); GLOAD(c1a, LTa, LBa, RTa, RBa);
            CLOAD(1, c0b, c1b); GLOAD(c1b, LTb, LBb, RTb, RBb);
            INTERP(0, c0a, LTa, LBa, RTa, RBa);
            CLOAD(2, c0a, c1a); GLOAD(c1a, LTa, LBa, RTa, RBa);
            INTERP(1, c0b, LTb, LBb, RTb, RBb);
            CLOAD(3, c0b, c1b); GLOAD(c1b, LTb, LBb, RTb, RBb);
            INTERP(2, c0a, LTa, LBa, RTa, RBa);
            INTERP(3, c0b, LTb, LBb, RTb, RBb);
        }
        __syncthreads();

        const unsigned short* As16 = (const unsigned short*)Asu;
        const unsigned short* Bs16 = (const unsigned short*)Bsu;
        #pragma unroll
        for (int s=0;s<4;s++){
            h16x8 a  = *(const h16x8*)(As16 + (s*2+half)*(AROW*2) + (32*w + l31)*8);
            h16x8 b0 = *(const h16x8*)(Bs16 + (l31*36 + s*8 + half*4)*2);
            h16x8 b1 = *(const h16x8*)(Bs16 + ((32+l31)*36 + s*8 + half*4)*2);
            acc0 = __builtin_amdgcn_mfma_f32_32x32x16_f16(a, b0, acc0, 0,0,0);
            acc1 = __builtin_amdgcn_mfma_f32_32x32x16_f16(a, b1, acc1, 0,0,0);
        }
        __syncthreads();
    }
#undef CLOAD
#undef GLOAD
#undef INTERP

    // epilogue: +db, ep[px][oc] u16 == dout2 row layout, straight copy out
    unsigned short* ep = (unsigned short*)smem_d;   // overlay (safe: barrier above)
    #pragma unroll
    for (int nt=0; nt<2; nt++){
        int oc = nt*32 + l31;
        float bias = db[oc];
        const f32x16& A = nt ? acc1 : acc0;
        #pragma unroll
        for (int rg=0; rg<4; rg++){
            int m0 = 32*w + 4*half + 8*rg;
            #pragma unroll
            for (int e=0;e<4;e++)
                ep[(m0+e)*64 + oc] = b16u(A[4*rg+e] + bias);
        }
    }
    __syncthreads();
    uint4* dst = (uint4*)((unsigned short*)dout2 + ((size_t)zb*128 + h)*(128*64));
    #pragma unroll
    for (int i=0;i<4;i++)
        dst[t + 256*i] = ((const uint4*)ep)[t + 256*i];
    #undef AROW
}

// ---------------------------------------------------------------------------
// K3b: 1x1 conv 256 -> 64 + cb + ReLU via f16 MFMA. grid (128 h, 4 b).
// A direct from dout2 (16-deep prefetch), B direct from L1-hot cwb2
// [kc][hf][oc][cl4]. Zero main-loop barriers.
// ---------------------------------------------------------------------------
__global__ __launch_bounds__(256,2) void k_combine_mfma(
    const f16* __restrict__ dout2,
    const unsigned* __restrict__ cwb2,  // [kc][hf][oc][cl4] u32
    const float* __restrict__ cb,
    float* __restrict__ out)
{
    int h = blockIdx.x, b = blockIdx.y;
    int t = threadIdx.x;
    int lane = t & 63, w = t >> 6, l31 = lane & 31, half = lane >> 5;

    __shared__ float ep2[64*132];   // 33.8 KB epilogue transpose

    f32x16 acc0, acc1;
    #pragma unroll
    for (int e=0;e<16;e++){ acc0[e]=0.f; acc1[e]=0.f; }

    const unsigned short* dbase0 = (const unsigned short*)dout2;
    const unsigned short* cb16 = (const unsigned short*)cwb2;
    size_t rowsel2 = ((size_t)b*128 + h)*128 + (32*w + l31);

    // issue all 16 A-fragment loads (16B each) up-front
    unsigned AV[64];
    #pragma unroll
    for (int kc=0; kc<16; kc++){
        *(uint4*)&AV[kc*4] = *(const uint4*)(
            dbase0 + (size_t)(kc>>2)*(4*HW*64) + rowsel2*64 + (kc&3)*16 + half*8);
    }
    #pragma unroll
    for (int kc=0; kc<16; kc++){
        h16x8 a  = __builtin_bit_cast(h16x8, *(uint4*)&AV[kc*4]);
        h16x8 b0 = *(const h16x8*)(cb16 + ((kc*2+half)*64 + l31)*8);
        h16x8 b1 = *(const h16x8*)(cb16 + ((kc*2+half)*64 + 32+l31)*8);
        acc0 = __builtin_amdgcn_mfma_f32_32x32x16_f16(a, b0, acc0, 0,0,0);
        acc1 = __builtin_amdgcn_mfma_f32_32x32x16_f16(a, b1, acc1, 0,0,0);
    }

    #pragma unroll
    for (int nt=0; nt<2; nt++){
        int oc = nt*32 + l31;
        float bias = cb[oc];
        const f32x16& A = nt ? acc1 : acc0;
        #pragma unroll
        for (int rg=0; rg<4; rg++){
            int m0 = 32*w + 4*half + 8*rg;
            #pragma unroll
            for (int e=0;e<4;e++)
                ep2[oc*132 + m0+e] = fmaxf(A[4*rg+e] + bias, 0.f);
        }
    }
    __syncthreads();
    for (int i=t; i<2048; i+=256){
        int oc = i>>5, sg = i&31;
        *(uint4*)&out[(((size_t)b*64+oc)*128 + h)*128 + sg*4] = *(const uint4*)&ep2[oc*132 + sg*4];
    }
}

extern "C" void kernel_launch(void* const* d_in, const int* in_sizes, int n_in,
                              void* d_out, int out_size, void* d_ws, size_t ws_size,
                              hipStream_t stream) {
    const float* x  = (const float*)d_in[0];
    const float* w1 = (const float*)d_in[1];
    const float* b1 = (const float*)d_in[2];
    const float* w2 = (const float*)d_in[3];
    const float* b2 = (const float*)d_in[4];
    const float* w3 = (const float*)d_in[5];
    const float* b3 = (const float*)d_in[6];
    const float* w4 = (const float*)d_in[7];
    const float* b4 = (const float*)d_in[8];
    const float* pw = (const float*)d_in[9];
    const float* pb = (const float*)d_in[10];
    const float* dw = (const float*)d_in[11];
    const float* db = (const float*)d_in[12];
    const float* cw = (const float*)d_in[13];
    const float* cb = (const float*)d_in[14];
    float* out = (float*)d_out;

    f16* feats2 = (f16*)d_ws;                               // 34.6 MB
    f16* offs   = feats2 + (size_t)16*FSL;                  // 9.4 MB
    f16* region2 = offs + (size_t)16*18*HW;
    f16* dout2  = region2;                                  // 33.55 MB
    unsigned* xt  = (unsigned*)region2;                     // 21.2 MB (dead before dout2)
    unsigned* wbt = xt + (size_t)4*8*XTD*XTD*8;             // 0.59 MB (dead before dout2)
    unsigned* dwb2 = (unsigned*)(dout2 + (size_t)16*128*128*64);  // 73.7 KB
    unsigned* cwb2 = dwb2 + 18432;                          // 32.8 KB
    unsigned* pwb  = cwb2 + 8192;                           // 36.9 KB

    k_prep        <<<dim3(1740),    256, 0, stream>>>(w1,w2,w3,w4, dw, cw, pw,
                                                      (uint4*)xt, wbt, dwb2, cwb2, pwb);
    k_xprep       <<<dim3(128,4),   256, 0, stream>>>(x, xt);
    k_branch_mfma <<<dim3(1024),    256, 0, stream>>>(xt, wbt, b1,b2,b3,b4, feats2);
    k_offset_mfma <<<dim3(2048),    256, 0, stream>>>(feats2, pwb, pb, offs);
    k_deform_mfma <<<dim3(2048),    256, 0, stream>>>(feats2, offs, dwb2, db, dout2);
    k_combine_mfma<<<dim3(128,4),   256, 0, stream>>>(dout2, cwb2, cb, out);
}